// Round 1
// baseline (735.577 us; speedup 1.0000x reference)
//
#include <hip/hip_runtime.h>

#define IN_F  128
#define HID_F 64
#define OUT_F 16

// ---------------------------------------------------------------------------
// 1. degrees: deg_out[src]++, deg_in[dst]++  (float atomics, exact for small counts)
// ---------------------------------------------------------------------------
__global__ __launch_bounds__(256) void degree_kernel(const int* __restrict__ src,
                                                     const int* __restrict__ dst,
                                                     float* __restrict__ deg_out,
                                                     float* __restrict__ deg_in, int E) {
    int e = blockIdx.x * 256 + threadIdx.x;
    if (e < E) {
        atomicAdd(&deg_out[src[e]], 1.0f);
        atomicAdd(&deg_in[dst[e]], 1.0f);
    }
}

// ---------------------------------------------------------------------------
// 2. norms in place: d = rsqrt(max(d,1))
// ---------------------------------------------------------------------------
__global__ __launch_bounds__(256) void norm_kernel(float* __restrict__ deg_out,
                                                   float* __restrict__ deg_in, int N) {
    int i = blockIdx.x * 256 + threadIdx.x;
    if (i < N) {
        deg_out[i] = rsqrtf(fmaxf(deg_out[i], 1.0f));
        deg_in[i]  = rsqrtf(fmaxf(deg_in[i], 1.0f));
    }
}

// ---------------------------------------------------------------------------
// 3. GEMM1: h[r][c] = sum_k x[r][k]*norm_s[r] * W1[k][c]   (128 -> 64)
//    block = 256 threads, 16 rows/block; W1 (32KB) + 16 x-rows (8KB) in LDS
// ---------------------------------------------------------------------------
__global__ __launch_bounds__(256) void gemm1_kernel(const float* __restrict__ x,
                                                    const float* __restrict__ W,
                                                    const float* __restrict__ norm_s,
                                                    float* __restrict__ h, int N) {
    __shared__ float sW[IN_F * HID_F];   // 32 KB
    __shared__ float sx[16][IN_F];       // 8 KB
    for (int i = threadIdx.x; i < IN_F * HID_F; i += 256) sW[i] = W[i];
    int row0 = blockIdx.x * 16;
    for (int i = threadIdx.x; i < 16 * IN_F; i += 256) {
        int r = i / IN_F, k = i % IN_F;
        int gr = row0 + r;
        sx[r][k] = (gr < N) ? x[(size_t)gr * IN_F + k] * norm_s[gr] : 0.0f;
    }
    __syncthreads();
    int col   = threadIdx.x & 63;
    int rbase = (threadIdx.x >> 6) * 4;   // 4 row-groups of 4 rows
    for (int rr = 0; rr < 4; rr++) {
        int r = rbase + rr;
        float acc = 0.0f;
        #pragma unroll 8
        for (int k = 0; k < IN_F; k++) acc += sx[r][k] * sW[k * HID_F + col];
        int gr = row0 + r;
        if (gr < N) h[(size_t)gr * HID_F + col] = acc;
    }
}

// ---------------------------------------------------------------------------
// 4. edge aggregation, 64 feats: one wave per edge (lane = feature)
// ---------------------------------------------------------------------------
__global__ __launch_bounds__(256) void agg64_kernel(const int* __restrict__ src,
                                                    const int* __restrict__ dst,
                                                    const float* __restrict__ h,
                                                    float* __restrict__ agg, int E) {
    int gid = blockIdx.x * 256 + threadIdx.x;
    int e = gid >> 6;
    int f = gid & 63;
    if (e < E) {
        float v = h[(size_t)src[e] * HID_F + f];
        atomicAdd(&agg[(size_t)dst[e] * HID_F + f], v);
    }
}

// ---------------------------------------------------------------------------
// 5. x1s = relu(agg1*norm_d + b1) * norm_s   (layer-2 input, prescaled)
// ---------------------------------------------------------------------------
__global__ __launch_bounds__(256) void relu_scale_kernel(const float* __restrict__ agg,
                                                         const float* __restrict__ norm_d,
                                                         const float* __restrict__ norm_s,
                                                         const float* __restrict__ b1,
                                                         float* __restrict__ x1s, int N) {
    int i = blockIdx.x * 256 + threadIdx.x;
    if (i < N * HID_F) {
        int r = i >> 6, c = i & 63;
        float v = agg[i] * norm_d[r] + b1[c];
        v = fmaxf(v, 0.0f);
        x1s[i] = v * norm_s[r];
    }
}

// ---------------------------------------------------------------------------
// 6. GEMM2: h2[r][c] = sum_k x1s[r][k] * W2[k][c]   (64 -> 16)
//    block = 256 threads, 32 rows/block
// ---------------------------------------------------------------------------
__global__ __launch_bounds__(256) void gemm2_kernel(const float* __restrict__ x,
                                                    const float* __restrict__ W,
                                                    float* __restrict__ h2, int N) {
    __shared__ float sW[HID_F * OUT_F];     // 4 KB
    __shared__ float sx[32][HID_F + 1];     // padded: +1 breaks 4-way bank alias
    for (int i = threadIdx.x; i < HID_F * OUT_F; i += 256) sW[i] = W[i];
    int row0 = blockIdx.x * 32;
    for (int i = threadIdx.x; i < 32 * HID_F; i += 256) {
        int r = i >> 6, k = i & 63;
        int gr = row0 + r;
        sx[r][k] = (gr < N) ? x[(size_t)gr * HID_F + k] : 0.0f;
    }
    __syncthreads();
    int col  = threadIdx.x & 15;
    int rgrp = threadIdx.x >> 4;            // 0..15, 2 rows each
    for (int rr = 0; rr < 2; rr++) {
        int r = rgrp * 2 + rr;
        float acc = 0.0f;
        #pragma unroll 8
        for (int k = 0; k < HID_F; k++) acc += sx[r][k] * sW[k * OUT_F + col];
        int gr = row0 + r;
        if (gr < N) h2[(size_t)gr * OUT_F + col] = acc;
    }
}

// ---------------------------------------------------------------------------
// 7. edge aggregation, 16 feats: 4 edges per wave
// ---------------------------------------------------------------------------
__global__ __launch_bounds__(256) void agg16_kernel(const int* __restrict__ src,
                                                    const int* __restrict__ dst,
                                                    const float* __restrict__ h,
                                                    float* __restrict__ agg, int E) {
    int gid = blockIdx.x * 256 + threadIdx.x;
    int e = gid >> 4;
    int f = gid & 15;
    if (e < E) {
        float v = h[(size_t)src[e] * OUT_F + f];
        atomicAdd(&agg[(size_t)dst[e] * OUT_F + f], v);
    }
}

// ---------------------------------------------------------------------------
// 8. epilogue: out = out*norm_d + b2  (in place on d_out)
// ---------------------------------------------------------------------------
__global__ __launch_bounds__(256) void epilogue_kernel(float* __restrict__ out,
                                                       const float* __restrict__ norm_d,
                                                       const float* __restrict__ b2, int N) {
    int i = blockIdx.x * 256 + threadIdx.x;
    if (i < N * OUT_F) {
        int r = i >> 4, c = i & 15;
        out[i] = out[i] * norm_d[r] + b2[c];
    }
}

extern "C" void kernel_launch(void* const* d_in, const int* in_sizes, int n_in,
                              void* d_out, int out_size, void* d_ws, size_t ws_size,
                              hipStream_t stream) {
    const float* feat = (const float*)d_in[0];
    const float* W1   = (const float*)d_in[1];
    const float* b1   = (const float*)d_in[2];
    const float* W2   = (const float*)d_in[3];
    const float* b2   = (const float*)d_in[4];
    const int*   src  = (const int*)d_in[5];
    const int*   dst  = (const int*)d_in[6];

    const int N = in_sizes[0] / IN_F;
    const int E = in_sizes[5];

    float* ws     = (float*)d_ws;
    float* norm_s = ws;                               // N
    float* norm_d = ws + N;                           // N
    float* h1     = ws + 2 * (size_t)N;               // N*64  (later x1s)
    float* agg1   = h1 + (size_t)N * HID_F;           // N*64  (later h2)
    float* out    = (float*)d_out;                    // N*16  (agg2 accumulates here)

    // zero accumulators (ws/out are poisoned 0xAA before every call)
    hipMemsetAsync(norm_s, 0, 2 * (size_t)N * sizeof(float), stream);
    hipMemsetAsync(agg1,  0, (size_t)N * HID_F * sizeof(float), stream);
    hipMemsetAsync(out,   0, (size_t)N * OUT_F * sizeof(float), stream);

    degree_kernel<<<(E + 255) / 256, 256, 0, stream>>>(src, dst, norm_s, norm_d, E);
    norm_kernel<<<(N + 255) / 256, 256, 0, stream>>>(norm_s, norm_d, N);

    // layer 1
    gemm1_kernel<<<(N + 15) / 16, 256, 0, stream>>>(feat, W1, norm_s, h1, N);
    {
        long long work = (long long)E * HID_F;
        agg64_kernel<<<(int)((work + 255) / 256), 256, 0, stream>>>(src, dst, h1, agg1, E);
    }
    relu_scale_kernel<<<(N * HID_F + 255) / 256, 256, 0, stream>>>(agg1, norm_d, norm_s, b1, h1, N);

    // layer 2 (h2 reuses agg1 buffer)
    float* x1s = h1;
    float* h2  = agg1;
    gemm2_kernel<<<(N + 31) / 32, 256, 0, stream>>>(x1s, W2, h2, N);
    {
        long long work = (long long)E * OUT_F;
        agg16_kernel<<<(int)((work + 255) / 256), 256, 0, stream>>>(src, dst, h2, out, E);
    }
    epilogue_kernel<<<(N * OUT_F + 255) / 256, 256, 0, stream>>>(out, norm_d, b2, N);
}

// Round 2
// 548.775 us; speedup vs baseline: 1.3404x; 1.3404x over previous
//
#include <hip/hip_runtime.h>

#define IN_F  128
#define HID_F 64
#define OUT_F 16

// ---------------------------------------------------------------------------
// 1. int histogram: deg_out[src]++, cnt_in[dst]++  (cnt_in doubles as row_start)
// ---------------------------------------------------------------------------
__global__ __launch_bounds__(256) void hist_kernel(const int* __restrict__ src,
                                                   const int* __restrict__ dst,
                                                   int* __restrict__ deg_out,
                                                   int* __restrict__ cnt_in, int E) {
    int e = blockIdx.x * 256 + threadIdx.x;
    if (e < E) {
        atomicAdd(&deg_out[src[e]], 1);
        atomicAdd(&cnt_in[dst[e]], 1);
    }
}

// ---------------------------------------------------------------------------
// 2. norms from int degrees: norm = rsqrt(max(deg,1))
// ---------------------------------------------------------------------------
__global__ __launch_bounds__(256) void norm_kernel(const int* __restrict__ deg_out,
                                                   const int* __restrict__ cnt_in,
                                                   float* __restrict__ norm_s,
                                                   float* __restrict__ norm_d, int N) {
    int i = blockIdx.x * 256 + threadIdx.x;
    if (i < N) {
        norm_s[i] = rsqrtf(fmaxf((float)deg_out[i], 1.0f));
        norm_d[i] = rsqrtf(fmaxf((float)cnt_in[i], 1.0f));
    }
}

// ---------------------------------------------------------------------------
// 3. single-block exclusive scan of counts -> row_start (in place), writes [N]=E
//    1024 threads, contiguous chunk per thread, Hillis-Steele on partials
// ---------------------------------------------------------------------------
__global__ __launch_bounds__(1024) void scan_kernel(int* __restrict__ counts, int N) {
    __shared__ int partial[1024];
    int t = threadIdx.x;
    int C = (N + 1023) / 1024;
    int lo = t * C, hi = min(lo + C, N);
    int sum = 0;
    for (int i = lo; i < hi; i++) sum += counts[i];
    partial[t] = sum;
    __syncthreads();
    for (int off = 1; off < 1024; off <<= 1) {
        int v = (t >= off) ? partial[t - off] : 0;
        __syncthreads();
        partial[t] += v;
        __syncthreads();
    }
    int run = (t > 0) ? partial[t - 1] : 0;
    for (int i = lo; i < hi; i++) { int c = counts[i]; counts[i] = run; run += c; }
    if (t == 1023) counts[N] = partial[1023];
}

// ---------------------------------------------------------------------------
// 4. scatter edges into CSR buckets (by dst)
// ---------------------------------------------------------------------------
__global__ __launch_bounds__(256) void scatter_kernel(const int* __restrict__ src,
                                                      const int* __restrict__ dst,
                                                      const int* __restrict__ row_start,
                                                      int* __restrict__ cursor,
                                                      int* __restrict__ csr_src, int E) {
    int e = blockIdx.x * 256 + threadIdx.x;
    if (e < E) {
        int d = dst[e];
        int pos = row_start[d] + atomicAdd(&cursor[d], 1);
        csr_src[pos] = src[e];
    }
}

// ---------------------------------------------------------------------------
// 5. GEMM1: h[r][c] = sum_k x[r][k]*norm_s[r] * W1[k][c]   (128 -> 64)
// ---------------------------------------------------------------------------
__global__ __launch_bounds__(256) void gemm1_kernel(const float* __restrict__ x,
                                                    const float* __restrict__ W,
                                                    const float* __restrict__ norm_s,
                                                    float* __restrict__ h, int N) {
    __shared__ float sW[IN_F * HID_F];   // 32 KB
    __shared__ float sx[16][IN_F];       // 8 KB
    for (int i = threadIdx.x; i < IN_F * HID_F; i += 256) sW[i] = W[i];
    int row0 = blockIdx.x * 16;
    for (int i = threadIdx.x; i < 16 * IN_F; i += 256) {
        int r = i / IN_F, k = i % IN_F;
        int gr = row0 + r;
        sx[r][k] = (gr < N) ? x[(size_t)gr * IN_F + k] * norm_s[gr] : 0.0f;
    }
    __syncthreads();
    int col   = threadIdx.x & 63;
    int rbase = (threadIdx.x >> 6) * 4;
    for (int rr = 0; rr < 4; rr++) {
        int r = rbase + rr;
        float acc = 0.0f;
        #pragma unroll 8
        for (int k = 0; k < IN_F; k++) acc += sx[r][k] * sW[k * HID_F + col];
        int gr = row0 + r;
        if (gr < N) h[(size_t)gr * HID_F + col] = acc;
    }
}

// ---------------------------------------------------------------------------
// 6. CSR aggregation layer 1 (64 feats) + fused epilogue:
//    x1s = relu(agg*norm_d + b1) * norm_s.  One wave per dst node, lane=feature.
// ---------------------------------------------------------------------------
__global__ __launch_bounds__(256) void agg1_kernel(const int* __restrict__ row_start,
                                                   const int* __restrict__ csr_src,
                                                   const float* __restrict__ h,
                                                   const float* __restrict__ norm_d,
                                                   const float* __restrict__ norm_s,
                                                   const float* __restrict__ b1,
                                                   float* __restrict__ x1s, int N) {
    int node = blockIdx.x * 4 + (threadIdx.x >> 6);
    if (node >= N) return;
    int lane = threadIdx.x & 63;
    int beg = row_start[node], end = row_start[node + 1];
    float acc0 = 0.0f, acc1 = 0.0f;
    int i = beg;
    for (; i + 1 < end; i += 2) {
        int s0 = csr_src[i], s1 = csr_src[i + 1];
        acc0 += h[(size_t)s0 * HID_F + lane];
        acc1 += h[(size_t)s1 * HID_F + lane];
    }
    if (i < end) acc0 += h[(size_t)csr_src[i] * HID_F + lane];
    float v = (acc0 + acc1) * norm_d[node] + b1[lane];
    v = fmaxf(v, 0.0f);
    x1s[(size_t)node * HID_F + lane] = v * norm_s[node];
}

// ---------------------------------------------------------------------------
// 7. GEMM2: h2[r][c] = sum_k x1s[r][k] * W2[k][c]   (64 -> 16)
// ---------------------------------------------------------------------------
__global__ __launch_bounds__(256) void gemm2_kernel(const float* __restrict__ x,
                                                    const float* __restrict__ W,
                                                    float* __restrict__ h2, int N) {
    __shared__ float sW[HID_F * OUT_F];     // 4 KB
    __shared__ float sx[32][HID_F + 1];
    for (int i = threadIdx.x; i < HID_F * OUT_F; i += 256) sW[i] = W[i];
    int row0 = blockIdx.x * 32;
    for (int i = threadIdx.x; i < 32 * HID_F; i += 256) {
        int r = i >> 6, k = i & 63;
        int gr = row0 + r;
        sx[r][k] = (gr < N) ? x[(size_t)gr * HID_F + k] : 0.0f;
    }
    __syncthreads();
    int col  = threadIdx.x & 15;
    int rgrp = threadIdx.x >> 4;
    for (int rr = 0; rr < 2; rr++) {
        int r = rgrp * 2 + rr;
        float acc = 0.0f;
        #pragma unroll 8
        for (int k = 0; k < HID_F; k++) acc += sx[r][k] * sW[k * OUT_F + col];
        int gr = row0 + r;
        if (gr < N) h2[(size_t)gr * OUT_F + col] = acc;
    }
}

// ---------------------------------------------------------------------------
// 8. CSR aggregation layer 2 (16 feats) + fused epilogue: out = agg*norm_d + b2
//    One wave per node; 4 edges x 16 feats per iteration; shfl reduce.
// ---------------------------------------------------------------------------
__global__ __launch_bounds__(256) void agg2_kernel(const int* __restrict__ row_start,
                                                   const int* __restrict__ csr_src,
                                                   const float* __restrict__ h2,
                                                   const float* __restrict__ norm_d,
                                                   const float* __restrict__ b2,
                                                   float* __restrict__ out, int N) {
    int node = blockIdx.x * 4 + (threadIdx.x >> 6);
    if (node >= N) return;
    int lane = threadIdx.x & 63;
    int f = lane & 15;
    int j = lane >> 4;                       // 0..3 sub-edge slot
    int beg = row_start[node], end = row_start[node + 1];
    float acc = 0.0f;
    for (int i = beg + j; i < end; i += 4)
        acc += h2[(size_t)csr_src[i] * OUT_F + f];
    acc += __shfl_xor(acc, 16);
    acc += __shfl_xor(acc, 32);
    if (j == 0)
        out[(size_t)node * OUT_F + f] = acc * norm_d[node] + b2[f];
}

extern "C" void kernel_launch(void* const* d_in, const int* in_sizes, int n_in,
                              void* d_out, int out_size, void* d_ws, size_t ws_size,
                              hipStream_t stream) {
    const float* feat = (const float*)d_in[0];
    const float* W1   = (const float*)d_in[1];
    const float* b1   = (const float*)d_in[2];
    const float* W2   = (const float*)d_in[3];
    const float* b2   = (const float*)d_in[4];
    const int*   src  = (const int*)d_in[5];
    const int*   dst  = (const int*)d_in[6];

    const int N = in_sizes[0] / IN_F;
    const int E = in_sizes[5];

    // workspace layout
    float* fws    = (float*)d_ws;
    float* norm_s = fws;                       // N
    float* norm_d = fws + N;                   // N
    float* h1     = fws + 2 * (size_t)N;       // N*64   (reused as h2: N*16)
    float* x1s    = h1 + (size_t)N * HID_F;    // N*64
    int*   iws    = (int*)(x1s + (size_t)N * HID_F);
    int*   deg_out   = iws;                    // N
    int*   row_start = iws + N;                // N+1
    int*   cursor    = iws + 2 * N + 1;        // N
    int*   csr_src   = iws + 3 * N + 1;        // E

    // zero the int counters (deg_out, row_start counts, cursor are contiguous)
    hipMemsetAsync(iws, 0, (size_t)(3 * N + 1) * sizeof(int), stream);

    // CSR build + norms
    hist_kernel<<<(E + 255) / 256, 256, 0, stream>>>(src, dst, deg_out, row_start, E);
    norm_kernel<<<(N + 255) / 256, 256, 0, stream>>>(deg_out, row_start, norm_s, norm_d, N);
    scan_kernel<<<1, 1024, 0, stream>>>(row_start, N);
    scatter_kernel<<<(E + 255) / 256, 256, 0, stream>>>(src, dst, row_start, cursor, csr_src, E);

    // layer 1
    gemm1_kernel<<<(N + 15) / 16, 256, 0, stream>>>(feat, W1, norm_s, h1, N);
    agg1_kernel<<<(N + 3) / 4, 256, 0, stream>>>(row_start, csr_src, h1, norm_d, norm_s, b1, x1s, N);

    // layer 2 (h2 reuses h1 buffer)
    float* h2 = h1;
    gemm2_kernel<<<(N + 31) / 32, 256, 0, stream>>>(x1s, W2, h2, N);
    agg2_kernel<<<(N + 3) / 4, 256, 0, stream>>>(row_start, csr_src, h2, norm_d, b2, (float*)d_out, N);
}

// Round 5
// 525.622 us; speedup vs baseline: 1.3994x; 1.0440x over previous
//
#include <hip/hip_runtime.h>

#define IN_F  128
#define HID_F 64
#define OUT_F 16

// ---------------------------------------------------------------------------
// 1. int histogram (4 edges/thread): deg_out[src]++, cnt_in[dst]++
// ---------------------------------------------------------------------------
__global__ __launch_bounds__(256) void hist_kernel(const int* __restrict__ src,
                                                   const int* __restrict__ dst,
                                                   int* __restrict__ deg_out,
                                                   int* __restrict__ cnt_in, int E) {
    int e0 = (blockIdx.x * 256 + threadIdx.x) * 4;
    if (e0 + 3 < E) {
        int4 s4 = *(const int4*)(src + e0);
        int4 d4 = *(const int4*)(dst + e0);
        atomicAdd(&deg_out[s4.x], 1); atomicAdd(&cnt_in[d4.x], 1);
        atomicAdd(&deg_out[s4.y], 1); atomicAdd(&cnt_in[d4.y], 1);
        atomicAdd(&deg_out[s4.z], 1); atomicAdd(&cnt_in[d4.z], 1);
        atomicAdd(&deg_out[s4.w], 1); atomicAdd(&cnt_in[d4.w], 1);
    } else {
        for (int e = e0; e < E; e++) {
            atomicAdd(&deg_out[src[e]], 1);
            atomicAdd(&cnt_in[dst[e]], 1);
        }
    }
}

// ---------------------------------------------------------------------------
// 2. norms from int degrees: norm = rsqrt(max(deg,1))
// ---------------------------------------------------------------------------
__global__ __launch_bounds__(256) void norm_kernel(const int* __restrict__ deg_out,
                                                   const int* __restrict__ cnt_in,
                                                   float* __restrict__ norm_s,
                                                   float* __restrict__ norm_d, int N) {
    int i = blockIdx.x * 256 + threadIdx.x;
    if (i < N) {
        norm_s[i] = rsqrtf(fmaxf((float)deg_out[i], 1.0f));
        norm_d[i] = rsqrtf(fmaxf((float)cnt_in[i], 1.0f));
    }
}

// ---------------------------------------------------------------------------
// 3. single-block exclusive scan of counts -> row_start (in place), writes [N]=E
// ---------------------------------------------------------------------------
__global__ __launch_bounds__(1024) void scan_kernel(int* __restrict__ counts, int N) {
    __shared__ int partial[1024];
    int t = threadIdx.x;
    int C = (N + 1023) / 1024;
    int lo = t * C, hi = min(lo + C, N);
    int sum = 0;
    for (int i = lo; i < hi; i++) sum += counts[i];
    partial[t] = sum;
    __syncthreads();
    for (int off = 1; off < 1024; off <<= 1) {
        int v = (t >= off) ? partial[t - off] : 0;
        __syncthreads();
        partial[t] += v;
        __syncthreads();
    }
    int run = (t > 0) ? partial[t - 1] : 0;
    for (int i = lo; i < hi; i++) { int c = counts[i]; counts[i] = run; run += c; }
    if (t == 1023) counts[N] = partial[1023];
}

// ---------------------------------------------------------------------------
// 4. scatter edges into CSR buckets (by dst), u16 payload, 4 edges/thread
// ---------------------------------------------------------------------------
__global__ __launch_bounds__(256) void scatter_kernel(const int* __restrict__ src,
                                                      const int* __restrict__ dst,
                                                      const int* __restrict__ row_start,
                                                      int* __restrict__ cursor,
                                                      unsigned short* __restrict__ csr_src, int E) {
    int e0 = (blockIdx.x * 256 + threadIdx.x) * 4;
    if (e0 + 3 < E) {
        int4 s4 = *(const int4*)(src + e0);
        int4 d4 = *(const int4*)(dst + e0);
        int ss[4] = {s4.x, s4.y, s4.z, s4.w};
        int dd[4] = {d4.x, d4.y, d4.z, d4.w};
        #pragma unroll
        for (int k = 0; k < 4; k++) {
            int d = dd[k];
            int pos = row_start[d] + atomicAdd(&cursor[d], 1);
            csr_src[pos] = (unsigned short)ss[k];
        }
    } else {
        for (int e = e0; e < E; e++) {
            int d = dst[e];
            int pos = row_start[d] + atomicAdd(&cursor[d], 1);
            csr_src[pos] = (unsigned short)src[e];
        }
    }
}

// ---------------------------------------------------------------------------
// 5. GEMM1: h[r][c] = sum_k x[r][k]*norm_s[r] * W1[k][c]   (128 -> 64)
// ---------------------------------------------------------------------------
__global__ __launch_bounds__(256) void gemm1_kernel(const float* __restrict__ x,
                                                    const float* __restrict__ W,
                                                    const float* __restrict__ norm_s,
                                                    float* __restrict__ h, int N) {
    __shared__ float sW[IN_F * HID_F];   // 32 KB
    __shared__ float sx[16][IN_F];       // 8 KB
    for (int i = threadIdx.x; i < IN_F * HID_F; i += 256) sW[i] = W[i];
    int row0 = blockIdx.x * 16;
    for (int i = threadIdx.x; i < 16 * IN_F; i += 256) {
        int r = i / IN_F, k = i % IN_F;
        int gr = row0 + r;
        sx[r][k] = (gr < N) ? x[(size_t)gr * IN_F + k] * norm_s[gr] : 0.0f;
    }
    __syncthreads();
    int col   = threadIdx.x & 63;
    int rbase = (threadIdx.x >> 6) * 4;
    for (int rr = 0; rr < 4; rr++) {
        int r = rbase + rr;
        float acc = 0.0f;
        #pragma unroll 8
        for (int k = 0; k < IN_F; k++) acc += sx[r][k] * sW[k * HID_F + col];
        int gr = row0 + r;
        if (gr < N) h[(size_t)gr * HID_F + col] = acc;
    }
}

// ---------------------------------------------------------------------------
// 6. CSR aggregation layer 1 (64 feats) + fused epilogue:
//    x1s = relu(agg*norm_d + b1) * norm_s.  One wave per dst node, lane=feature.
//    x4 unroll, 4 independent accumulators for memory-level parallelism.
// ---------------------------------------------------------------------------
__global__ __launch_bounds__(256) void agg1_kernel(const int* __restrict__ row_start,
                                                   const unsigned short* __restrict__ csr_src,
                                                   const float* __restrict__ h,
                                                   const float* __restrict__ norm_d,
                                                   const float* __restrict__ norm_s,
                                                   const float* __restrict__ b1,
                                                   float* __restrict__ x1s, int N) {
    int node = blockIdx.x * 4 + (threadIdx.x >> 6);
    if (node >= N) return;
    int lane = threadIdx.x & 63;
    int beg = row_start[node], end = row_start[node + 1];
    float a0 = 0.f, a1 = 0.f, a2 = 0.f, a3 = 0.f;
    int i = beg;
    for (; i + 3 < end; i += 4) {
        int s0 = (int)csr_src[i],     s1 = (int)csr_src[i + 1];
        int s2 = (int)csr_src[i + 2], s3 = (int)csr_src[i + 3];
        a0 += h[(size_t)s0 * HID_F + lane];
        a1 += h[(size_t)s1 * HID_F + lane];
        a2 += h[(size_t)s2 * HID_F + lane];
        a3 += h[(size_t)s3 * HID_F + lane];
    }
    for (; i < end; i++) a0 += h[(size_t)csr_src[i] * HID_F + lane];
    float v = ((a0 + a1) + (a2 + a3)) * norm_d[node] + b1[lane];
    v = fmaxf(v, 0.0f);
    x1s[(size_t)node * HID_F + lane] = v * norm_s[node];
}

// ---------------------------------------------------------------------------
// 7. GEMM2: h2[r][c] = sum_k x1s[r][k] * W2[k][c]   (64 -> 16)
// ---------------------------------------------------------------------------
__global__ __launch_bounds__(256) void gemm2_kernel(const float* __restrict__ x,
                                                    const float* __restrict__ W,
                                                    float* __restrict__ h2, int N) {
    __shared__ float sW[HID_F * OUT_F];
    __shared__ float sx[32][HID_F + 1];
    for (int i = threadIdx.x; i < HID_F * OUT_F; i += 256) sW[i] = W[i];
    int row0 = blockIdx.x * 32;
    for (int i = threadIdx.x; i < 32 * HID_F; i += 256) {
        int r = i >> 6, k = i & 63;
        int gr = row0 + r;
        sx[r][k] = (gr < N) ? x[(size_t)gr * HID_F + k] : 0.0f;
    }
    __syncthreads();
    int col  = threadIdx.x & 15;
    int rgrp = threadIdx.x >> 4;
    for (int rr = 0; rr < 2; rr++) {
        int r = rgrp * 2 + rr;
        float acc = 0.0f;
        #pragma unroll 8
        for (int k = 0; k < HID_F; k++) acc += sx[r][k] * sW[k * OUT_F + col];
        int gr = row0 + r;
        if (gr < N) h2[(size_t)gr * OUT_F + col] = acc;
    }
}

// ---------------------------------------------------------------------------
// 8. CSR aggregation layer 2 (16 feats) + fused epilogue: out = agg*norm_d + b2
//    One wave per node; 4 edge-slots x 16 feats; shfl reduce.
// ---------------------------------------------------------------------------
__global__ __launch_bounds__(256) void agg2_kernel(const int* __restrict__ row_start,
                                                   const unsigned short* __restrict__ csr_src,
                                                   const float* __restrict__ h2,
                                                   const float* __restrict__ norm_d,
                                                   const float* __restrict__ b2,
                                                   float* __restrict__ out, int N) {
    int node = blockIdx.x * 4 + (threadIdx.x >> 6);
    if (node >= N) return;
    int lane = threadIdx.x & 63;
    int f = lane & 15;
    int j = lane >> 4;                       // 0..3 sub-edge slot
    int beg = row_start[node], end = row_start[node + 1];
    float acc = 0.0f;
    for (int i = beg + j; i < end; i += 4)
        acc += h2[(size_t)csr_src[i] * OUT_F + f];
    acc += __shfl_xor(acc, 16);
    acc += __shfl_xor(acc, 32);
    if (j == 0)
        out[(size_t)node * OUT_F + f] = acc * norm_d[node] + b2[f];
}

extern "C" void kernel_launch(void* const* d_in, const int* in_sizes, int n_in,
                              void* d_out, int out_size, void* d_ws, size_t ws_size,
                              hipStream_t stream) {
    const float* feat = (const float*)d_in[0];
    const float* W1   = (const float*)d_in[1];
    const float* b1   = (const float*)d_in[2];
    const float* W2   = (const float*)d_in[3];
    const float* b2   = (const float*)d_in[4];
    const int*   src  = (const int*)d_in[5];
    const int*   dst  = (const int*)d_in[6];

    const int N = in_sizes[0] / IN_F;
    const int E = in_sizes[5];

    // workspace layout (~29.8 MB; round-2's proven footprint was 33.0 MB)
    float* fws    = (float*)d_ws;
    float* norm_s = fws;                       // N
    float* norm_d = fws + N;                   // N
    float* h1     = fws + 2 * (size_t)N;       // N*64  (reused as h2: N*16)
    float* x1s    = h1 + (size_t)N * HID_F;    // N*64
    int*   iws    = (int*)(x1s + (size_t)N * HID_F);
    int*   deg_out   = iws;                    // N
    int*   row_start = iws + N;                // N+1 (counts first, then scanned in place)
    int*   cursor    = iws + 2 * N + 1;        // N
    unsigned short* csr_src = (unsigned short*)(iws + 3 * N + 1); // E u16

    // zero the int counters (deg_out, row_start counts, cursor contiguous)
    hipMemsetAsync(iws, 0, (size_t)(3 * N + 1) * sizeof(int), stream);

    // CSR build + norms
    hist_kernel<<<(E + 1023) / 1024, 256, 0, stream>>>(src, dst, deg_out, row_start, E);
    norm_kernel<<<(N + 255) / 256, 256, 0, stream>>>(deg_out, row_start, norm_s, norm_d, N);
    scan_kernel<<<1, 1024, 0, stream>>>(row_start, N);
    scatter_kernel<<<(E + 1023) / 1024, 256, 0, stream>>>(src, dst, row_start, cursor, csr_src, E);

    // layer 1
    gemm1_kernel<<<(N + 15) / 16, 256, 0, stream>>>(feat, W1, norm_s, h1, N);
    agg1_kernel<<<(N + 3) / 4, 256, 0, stream>>>(row_start, csr_src, h1, norm_d, norm_s, b1, x1s, N);

    // layer 2 (h2 reuses h1 buffer)
    float* h2 = h1;
    gemm2_kernel<<<(N + 31) / 32, 256, 0, stream>>>(x1s, W2, h2, N);
    agg2_kernel<<<(N + 3) / 4, 256, 0, stream>>>(row_start, csr_src, h2, norm_d, b2, (float*)d_out, N);
}

// Round 6
// 396.112 us; speedup vs baseline: 1.8570x; 1.3270x over previous
//
#include <hip/hip_runtime.h>

#define IN_F  128
#define HID_F 64
#define OUT_F 16
#define MAX_N 50176          // max nodes supported by LDS tables (25088 u32 words = 100.4 KB)
#define HWORDS (MAX_N / 2)
#define NSEG  64             // edge segments (one block each in hist/scatter)

// ---------------------------------------------------------------------------
// 1. per-segment LDS histogram (packed u16 halfwords), no global atomics.
//    partial[b][w] = packed counts of nodes {2w, 2w+1} within segment b.
// ---------------------------------------------------------------------------
__global__ __launch_bounds__(1024) void hist_lds_kernel(const int* __restrict__ ids,
                                                        unsigned int* __restrict__ partial,
                                                        int E, int seg, int Wr) {
    __shared__ unsigned int cnt[HWORDS];
    int b = blockIdx.x;
    for (int w = threadIdx.x; w < Wr; w += 1024) cnt[w] = 0;
    __syncthreads();
    int lo = b * seg, hi = min(lo + seg, E);
    for (int e = lo + threadIdx.x; e < hi; e += 1024) {
        int d = ids[e];
        atomicAdd(&cnt[d >> 1], 1u << ((d & 1) * 16));   // LDS atomic
    }
    __syncthreads();
    for (int w = threadIdx.x; w < Wr; w += 1024)
        partial[(size_t)b * Wr + w] = cnt[w];
}

// ---------------------------------------------------------------------------
// 2. reduce partials -> per-node totals; rewrite partials in place as
//    per-(segment,node) EXCLUSIVE prefix (fits u16: <= max degree).
// ---------------------------------------------------------------------------
__global__ __launch_bounds__(256) void reduce_prefix_kernel(unsigned int* __restrict__ partial,
                                                            int* __restrict__ totals,
                                                            int Wr, int N) {
    int w = blockIdx.x * 256 + threadIdx.x;
    if (w >= Wr) return;
    unsigned int r0 = 0, r1 = 0;
    for (int b = 0; b < NSEG; b++) {
        size_t idx = (size_t)b * Wr + w;
        unsigned int v = partial[idx];
        partial[idx] = r0 | (r1 << 16);
        r0 += v & 0xFFFFu;
        r1 += v >> 16;
    }
    int d0 = 2 * w, d1 = 2 * w + 1;
    if (d0 < N) totals[d0] = (int)r0;
    if (d1 < N) totals[d1] = (int)r1;
}

// ---------------------------------------------------------------------------
// 3. norms from int degrees: norm = rsqrt(max(deg,1))
// ---------------------------------------------------------------------------
__global__ __launch_bounds__(256) void norm_kernel(const int* __restrict__ deg_out,
                                                   const int* __restrict__ cnt_in,
                                                   float* __restrict__ norm_s,
                                                   float* __restrict__ norm_d, int N) {
    int i = blockIdx.x * 256 + threadIdx.x;
    if (i < N) {
        norm_s[i] = rsqrtf(fmaxf((float)deg_out[i], 1.0f));
        norm_d[i] = rsqrtf(fmaxf((float)cnt_in[i], 1.0f));
    }
}

// ---------------------------------------------------------------------------
// 4. single-block exclusive scan of counts -> row_start (in place), writes [N]=E
// ---------------------------------------------------------------------------
__global__ __launch_bounds__(1024) void scan_kernel(int* __restrict__ counts, int N) {
    __shared__ int partial[1024];
    int t = threadIdx.x;
    int C = (N + 1023) / 1024;
    int lo = t * C, hi = min(lo + C, N);
    int sum = 0;
    for (int i = lo; i < hi; i++) sum += counts[i];
    partial[t] = sum;
    __syncthreads();
    for (int off = 1; off < 1024; off <<= 1) {
        int v = (t >= off) ? partial[t - off] : 0;
        __syncthreads();
        partial[t] += v;
        __syncthreads();
    }
    int run = (t > 0) ? partial[t - 1] : 0;
    for (int i = lo; i < hi; i++) { int c = counts[i]; counts[i] = run; run += c; }
    if (t == 1023) counts[N] = partial[1023];
}

// ---------------------------------------------------------------------------
// 5. scatter via LDS cursors: block b owns edge segment b; cursor LDS word
//    preloaded with row_start[d] + prefix[b][d]; slots claimed by LDS atomic.
//    Two node-range passes (25088 nodes/pass). No global atomics.
// ---------------------------------------------------------------------------
__global__ __launch_bounds__(1024) void scatter_lds_kernel(const int* __restrict__ src,
                                                           const int* __restrict__ dst,
                                                           const int* __restrict__ row_start,
                                                           const unsigned int* __restrict__ prefix,
                                                           unsigned short* __restrict__ csr_src,
                                                           int E, int seg, int Wr, int N) {
    __shared__ unsigned int pos[HWORDS];
    int b = blockIdx.x;
    int lo = b * seg, hi = min(lo + seg, E);
    for (int p = 0; p * HWORDS < N; p++) {
        int nlo = p * HWORDS, nhi = min(nlo + HWORDS, N);
        for (int d = nlo + threadIdx.x; d < nhi; d += 1024) {
            unsigned int word = prefix[(size_t)b * Wr + (d >> 1)];
            unsigned int base16 = (word >> ((d & 1) * 16)) & 0xFFFFu;
            pos[d - nlo] = (unsigned int)row_start[d] + base16;
        }
        __syncthreads();
        for (int e = lo + threadIdx.x; e < hi; e += 1024) {
            int d = dst[e];
            if (d >= nlo && d < nhi) {
                unsigned int q = atomicAdd(&pos[d - nlo], 1u);   // LDS atomic
                csr_src[q] = (unsigned short)src[e];
            }
        }
        __syncthreads();
    }
}

// ---------------------------------------------------------------------------
// 6. GEMM1: h[r][c] = sum_k x[r][k]*norm_s[r] * W1[k][c]   (128 -> 64)
// ---------------------------------------------------------------------------
__global__ __launch_bounds__(256) void gemm1_kernel(const float* __restrict__ x,
                                                    const float* __restrict__ W,
                                                    const float* __restrict__ norm_s,
                                                    float* __restrict__ h, int N) {
    __shared__ float sW[IN_F * HID_F];   // 32 KB
    __shared__ float sx[16][IN_F];       // 8 KB
    for (int i = threadIdx.x; i < IN_F * HID_F; i += 256) sW[i] = W[i];
    int row0 = blockIdx.x * 16;
    for (int i = threadIdx.x; i < 16 * IN_F; i += 256) {
        int r = i / IN_F, k = i % IN_F;
        int gr = row0 + r;
        sx[r][k] = (gr < N) ? x[(size_t)gr * IN_F + k] * norm_s[gr] : 0.0f;
    }
    __syncthreads();
    int col   = threadIdx.x & 63;
    int rbase = (threadIdx.x >> 6) * 4;
    for (int rr = 0; rr < 4; rr++) {
        int r = rbase + rr;
        float acc = 0.0f;
        #pragma unroll 8
        for (int k = 0; k < IN_F; k++) acc += sx[r][k] * sW[k * HID_F + col];
        int gr = row0 + r;
        if (gr < N) h[(size_t)gr * HID_F + col] = acc;
    }
}

// ---------------------------------------------------------------------------
// 7. CSR aggregation layer 1 (64 feats) + fused epilogue
// ---------------------------------------------------------------------------
__global__ __launch_bounds__(256) void agg1_kernel(const int* __restrict__ row_start,
                                                   const unsigned short* __restrict__ csr_src,
                                                   const float* __restrict__ h,
                                                   const float* __restrict__ norm_d,
                                                   const float* __restrict__ norm_s,
                                                   const float* __restrict__ b1,
                                                   float* __restrict__ x1s, int N) {
    int node = blockIdx.x * 4 + (threadIdx.x >> 6);
    if (node >= N) return;
    int lane = threadIdx.x & 63;
    int beg = row_start[node], end = row_start[node + 1];
    float a0 = 0.f, a1 = 0.f, a2 = 0.f, a3 = 0.f;
    int i = beg;
    for (; i + 3 < end; i += 4) {
        int s0 = (int)csr_src[i],     s1 = (int)csr_src[i + 1];
        int s2 = (int)csr_src[i + 2], s3 = (int)csr_src[i + 3];
        a0 += h[(size_t)s0 * HID_F + lane];
        a1 += h[(size_t)s1 * HID_F + lane];
        a2 += h[(size_t)s2 * HID_F + lane];
        a3 += h[(size_t)s3 * HID_F + lane];
    }
    for (; i < end; i++) a0 += h[(size_t)csr_src[i] * HID_F + lane];
    float v = ((a0 + a1) + (a2 + a3)) * norm_d[node] + b1[lane];
    v = fmaxf(v, 0.0f);
    x1s[(size_t)node * HID_F + lane] = v * norm_s[node];
}

// ---------------------------------------------------------------------------
// 8. GEMM2: h2[r][c] = sum_k x1s[r][k] * W2[k][c]   (64 -> 16)
// ---------------------------------------------------------------------------
__global__ __launch_bounds__(256) void gemm2_kernel(const float* __restrict__ x,
                                                    const float* __restrict__ W,
                                                    float* __restrict__ h2, int N) {
    __shared__ float sW[HID_F * OUT_F];
    __shared__ float sx[32][HID_F + 1];
    for (int i = threadIdx.x; i < HID_F * OUT_F; i += 256) sW[i] = W[i];
    int row0 = blockIdx.x * 32;
    for (int i = threadIdx.x; i < 32 * HID_F; i += 256) {
        int r = i >> 6, k = i & 63;
        int gr = row0 + r;
        sx[r][k] = (gr < N) ? x[(size_t)gr * HID_F + k] : 0.0f;
    }
    __syncthreads();
    int col  = threadIdx.x & 15;
    int rgrp = threadIdx.x >> 4;
    for (int rr = 0; rr < 2; rr++) {
        int r = rgrp * 2 + rr;
        float acc = 0.0f;
        #pragma unroll 8
        for (int k = 0; k < HID_F; k++) acc += sx[r][k] * sW[k * OUT_F + col];
        int gr = row0 + r;
        if (gr < N) h2[(size_t)gr * OUT_F + col] = acc;
    }
}

// ---------------------------------------------------------------------------
// 9. CSR aggregation layer 2 (16 feats) + fused epilogue
// ---------------------------------------------------------------------------
__global__ __launch_bounds__(256) void agg2_kernel(const int* __restrict__ row_start,
                                                   const unsigned short* __restrict__ csr_src,
                                                   const float* __restrict__ h2,
                                                   const float* __restrict__ norm_d,
                                                   const float* __restrict__ b2,
                                                   float* __restrict__ out, int N) {
    int node = blockIdx.x * 4 + (threadIdx.x >> 6);
    if (node >= N) return;
    int lane = threadIdx.x & 63;
    int f = lane & 15;
    int j = lane >> 4;
    int beg = row_start[node], end = row_start[node + 1];
    float acc = 0.0f;
    for (int i = beg + j; i < end; i += 4)
        acc += h2[(size_t)csr_src[i] * OUT_F + f];
    acc += __shfl_xor(acc, 16);
    acc += __shfl_xor(acc, 32);
    if (j == 0)
        out[(size_t)node * OUT_F + f] = acc * norm_d[node] + b2[f];
}

extern "C" void kernel_launch(void* const* d_in, const int* in_sizes, int n_in,
                              void* d_out, int out_size, void* d_ws, size_t ws_size,
                              hipStream_t stream) {
    const float* feat = (const float*)d_in[0];
    const float* W1   = (const float*)d_in[1];
    const float* b1   = (const float*)d_in[2];
    const float* W2   = (const float*)d_in[3];
    const float* b2   = (const float*)d_in[4];
    const int*   src  = (const int*)d_in[5];
    const int*   dst  = (const int*)d_in[6];

    const int N   = in_sizes[0] / IN_F;       // 50000 (<= MAX_N)
    const int E   = in_sizes[5];              // 1.6M
    const int seg = (E + NSEG - 1) / NSEG;    // edges per segment
    const int Wr  = (N + 1) >> 1;             // packed histogram words

    // ---- workspace layout (~36 MB) ----
    float* fws    = (float*)d_ws;
    float* norm_s = fws;                       // N
    float* norm_d = fws + N;                   // N
    float* h1     = fws + 2 * (size_t)N;       // N*64  (reused as h2: N*16)
    float* x1s    = h1 + (size_t)N * HID_F;    // N*64
    int*   iws    = (int*)(x1s + (size_t)N * HID_F);
    int*   deg_out   = iws;                    // N
    int*   row_start = iws + N;                // N+1 (counts, then scanned in place)
    unsigned int* partial = (unsigned int*)(iws + 2 * N + 1);      // NSEG*Wr
    unsigned short* csr_src = (unsigned short*)(partial + (size_t)NSEG * Wr); // E u16

    // graph build: LDS histograms (no global atomics, no memsets needed)
    hist_lds_kernel<<<NSEG, 1024, 0, stream>>>(src, partial, E, seg, Wr);
    reduce_prefix_kernel<<<(Wr + 255) / 256, 256, 0, stream>>>(partial, deg_out, Wr, N);
    hist_lds_kernel<<<NSEG, 1024, 0, stream>>>(dst, partial, E, seg, Wr);
    reduce_prefix_kernel<<<(Wr + 255) / 256, 256, 0, stream>>>(partial, row_start, Wr, N);
    norm_kernel<<<(N + 255) / 256, 256, 0, stream>>>(deg_out, row_start, norm_s, norm_d, N);
    scan_kernel<<<1, 1024, 0, stream>>>(row_start, N);
    scatter_lds_kernel<<<NSEG, 1024, 0, stream>>>(src, dst, row_start, partial, csr_src, E, seg, Wr, N);

    // layer 1
    gemm1_kernel<<<(N + 15) / 16, 256, 0, stream>>>(feat, W1, norm_s, h1, N);
    agg1_kernel<<<(N + 3) / 4, 256, 0, stream>>>(row_start, csr_src, h1, norm_d, norm_s, b1, x1s, N);

    // layer 2 (h2 reuses h1 buffer)
    float* h2 = h1;
    gemm2_kernel<<<(N + 31) / 32, 256, 0, stream>>>(x1s, W2, h2, N);
    agg2_kernel<<<(N + 3) / 4, 256, 0, stream>>>(row_start, csr_src, h2, norm_d, b2, (float*)d_out, N);
}

// Round 7
// 329.369 us; speedup vs baseline: 2.2333x; 1.2026x over previous
//
#include <hip/hip_runtime.h>

#define IN_F  128
#define HID_F 64
#define OUT_F 16
#define MAX_N 50176          // max nodes supported by LDS tables (25088 u32 words = 100.4 KB)
#define HWORDS (MAX_N / 2)
#define NSEG  64             // edge segments (one block each in hist/scatter)

#define SCAN_ELEMS 4
#define SCAN_BLOCK 256
#define SCAN_CHUNK (SCAN_BLOCK * SCAN_ELEMS)   // 1024 elements per block

// ---------------------------------------------------------------------------
// 1. per-segment LDS histogram (packed u16 halfwords), no global atomics.
// ---------------------------------------------------------------------------
__global__ __launch_bounds__(1024) void hist_lds_kernel(const int* __restrict__ ids,
                                                        unsigned int* __restrict__ partial,
                                                        int E, int seg, int Wr) {
    __shared__ unsigned int cnt[HWORDS];
    int b = blockIdx.x;
    for (int w = threadIdx.x; w < Wr; w += 1024) cnt[w] = 0;
    __syncthreads();
    int lo = b * seg, hi = min(lo + seg, E);
    for (int e = lo + threadIdx.x; e < hi; e += 1024) {
        int d = ids[e];
        atomicAdd(&cnt[d >> 1], 1u << ((d & 1) * 16));   // LDS atomic
    }
    __syncthreads();
    for (int w = threadIdx.x; w < Wr; w += 1024)
        partial[(size_t)b * Wr + w] = cnt[w];
}

// ---------------------------------------------------------------------------
// 2. reduce partials -> per-node totals; rewrite partials in place as
//    per-(segment,node) EXCLUSIVE prefix (fits u16).
// ---------------------------------------------------------------------------
__global__ __launch_bounds__(256) void reduce_prefix_kernel(unsigned int* __restrict__ partial,
                                                            int* __restrict__ totals,
                                                            int Wr, int N) {
    int w = blockIdx.x * 256 + threadIdx.x;
    if (w >= Wr) return;
    unsigned int r0 = 0, r1 = 0;
    for (int b = 0; b < NSEG; b++) {
        size_t idx = (size_t)b * Wr + w;
        unsigned int v = partial[idx];
        partial[idx] = r0 | (r1 << 16);
        r0 += v & 0xFFFFu;
        r1 += v >> 16;
    }
    int d0 = 2 * w, d1 = 2 * w + 1;
    if (d0 < N) totals[d0] = (int)r0;
    if (d1 < N) totals[d1] = (int)r1;
}

// ---------------------------------------------------------------------------
// 3. norms from int degrees: norm = rsqrt(max(deg,1))
// ---------------------------------------------------------------------------
__global__ __launch_bounds__(256) void norm_kernel(const int* __restrict__ deg_out,
                                                   const int* __restrict__ cnt_in,
                                                   float* __restrict__ norm_s,
                                                   float* __restrict__ norm_d, int N) {
    int i = blockIdx.x * 256 + threadIdx.x;
    if (i < N) {
        norm_s[i] = rsqrtf(fmaxf((float)deg_out[i], 1.0f));
        norm_d[i] = rsqrtf(fmaxf((float)cnt_in[i], 1.0f));
    }
}

// ---------------------------------------------------------------------------
// 4a. multi-block scan phase 1: local exclusive scan per 1024-elem chunk
// ---------------------------------------------------------------------------
__global__ __launch_bounds__(SCAN_BLOCK) void scan_local_kernel(int* __restrict__ counts,
                                                                int* __restrict__ bsum, int N) {
    __shared__ int part[SCAN_BLOCK];
    int t = threadIdx.x;
    int base = blockIdx.x * SCAN_CHUNK + t * SCAN_ELEMS;
    int v[SCAN_ELEMS];
    int s = 0;
    #pragma unroll
    for (int k = 0; k < SCAN_ELEMS; k++) {
        int i = base + k;
        v[k] = (i < N) ? counts[i] : 0;
        s += v[k];
    }
    part[t] = s;
    __syncthreads();
    for (int off = 1; off < SCAN_BLOCK; off <<= 1) {
        int x = (t >= off) ? part[t - off] : 0;
        __syncthreads();
        part[t] += x;
        __syncthreads();
    }
    int run = (t > 0) ? part[t - 1] : 0;
    #pragma unroll
    for (int k = 0; k < SCAN_ELEMS; k++) {
        int i = base + k;
        if (i < N) counts[i] = run;
        run += v[k];
    }
    if (t == SCAN_BLOCK - 1) bsum[blockIdx.x] = part[SCAN_BLOCK - 1];
}

// ---------------------------------------------------------------------------
// 4b. scan phase 2: single tiny block scans the chunk totals (<=1024 chunks),
//     rewrites bsum as exclusive offsets, writes grand total to rowN (=E)
// ---------------------------------------------------------------------------
__global__ __launch_bounds__(1024) void scan_bsum_kernel(int* __restrict__ bsum,
                                                         int* __restrict__ rowN, int nblocks) {
    __shared__ int part[1024];
    int t = threadIdx.x;
    int v = (t < nblocks) ? bsum[t] : 0;
    part[t] = v;
    __syncthreads();
    for (int off = 1; off < 1024; off <<= 1) {
        int x = (t >= off) ? part[t - off] : 0;
        __syncthreads();
        part[t] += x;
        __syncthreads();
    }
    if (t < nblocks) bsum[t] = part[t] - v;   // exclusive
    if (t == 1023) *rowN = part[1023];
}

// ---------------------------------------------------------------------------
// 4c. scan phase 3: add chunk offsets
// ---------------------------------------------------------------------------
__global__ __launch_bounds__(256) void scan_add_kernel(int* __restrict__ counts,
                                                       const int* __restrict__ bsum, int N) {
    int i = blockIdx.x * 256 + threadIdx.x;
    if (i < N) counts[i] += bsum[i / SCAN_CHUNK];
}

// ---------------------------------------------------------------------------
// 5. scatter via LDS cursors (no global atomics)
// ---------------------------------------------------------------------------
__global__ __launch_bounds__(1024) void scatter_lds_kernel(const int* __restrict__ src,
                                                           const int* __restrict__ dst,
                                                           const int* __restrict__ row_start,
                                                           const unsigned int* __restrict__ prefix,
                                                           unsigned short* __restrict__ csr_src,
                                                           int E, int seg, int Wr, int N) {
    __shared__ unsigned int pos[HWORDS];
    int b = blockIdx.x;
    int lo = b * seg, hi = min(lo + seg, E);
    for (int p = 0; p * HWORDS < N; p++) {
        int nlo = p * HWORDS, nhi = min(nlo + HWORDS, N);
        for (int d = nlo + threadIdx.x; d < nhi; d += 1024) {
            unsigned int word = prefix[(size_t)b * Wr + (d >> 1)];
            unsigned int base16 = (word >> ((d & 1) * 16)) & 0xFFFFu;
            pos[d - nlo] = (unsigned int)row_start[d] + base16;
        }
        __syncthreads();
        for (int e = lo + threadIdx.x; e < hi; e += 1024) {
            int d = dst[e];
            if (d >= nlo && d < nhi) {
                unsigned int q = atomicAdd(&pos[d - nlo], 1u);   // LDS atomic
                csr_src[q] = (unsigned short)src[e];
            }
        }
        __syncthreads();
    }
}

// ---------------------------------------------------------------------------
// 6. GEMM1 (128 -> 64)
// ---------------------------------------------------------------------------
__global__ __launch_bounds__(256) void gemm1_kernel(const float* __restrict__ x,
                                                    const float* __restrict__ W,
                                                    const float* __restrict__ norm_s,
                                                    float* __restrict__ h, int N) {
    __shared__ float sW[IN_F * HID_F];   // 32 KB
    __shared__ float sx[16][IN_F];       // 8 KB
    for (int i = threadIdx.x; i < IN_F * HID_F; i += 256) sW[i] = W[i];
    int row0 = blockIdx.x * 16;
    for (int i = threadIdx.x; i < 16 * IN_F; i += 256) {
        int r = i / IN_F, k = i % IN_F;
        int gr = row0 + r;
        sx[r][k] = (gr < N) ? x[(size_t)gr * IN_F + k] * norm_s[gr] : 0.0f;
    }
    __syncthreads();
    int col   = threadIdx.x & 63;
    int rbase = (threadIdx.x >> 6) * 4;
    for (int rr = 0; rr < 4; rr++) {
        int r = rbase + rr;
        float acc = 0.0f;
        #pragma unroll 8
        for (int k = 0; k < IN_F; k++) acc += sx[r][k] * sW[k * HID_F + col];
        int gr = row0 + r;
        if (gr < N) h[(size_t)gr * HID_F + col] = acc;
    }
}

// ---------------------------------------------------------------------------
// 7. CSR aggregation layer 1 (64 feats) + fused epilogue
// ---------------------------------------------------------------------------
__global__ __launch_bounds__(256) void agg1_kernel(const int* __restrict__ row_start,
                                                   const unsigned short* __restrict__ csr_src,
                                                   const float* __restrict__ h,
                                                   const float* __restrict__ norm_d,
                                                   const float* __restrict__ norm_s,
                                                   const float* __restrict__ b1,
                                                   float* __restrict__ x1s, int N) {
    int node = blockIdx.x * 4 + (threadIdx.x >> 6);
    if (node >= N) return;
    int lane = threadIdx.x & 63;
    int beg = row_start[node], end = row_start[node + 1];
    float a0 = 0.f, a1 = 0.f, a2 = 0.f, a3 = 0.f;
    int i = beg;
    for (; i + 3 < end; i += 4) {
        int s0 = (int)csr_src[i],     s1 = (int)csr_src[i + 1];
        int s2 = (int)csr_src[i + 2], s3 = (int)csr_src[i + 3];
        a0 += h[(size_t)s0 * HID_F + lane];
        a1 += h[(size_t)s1 * HID_F + lane];
        a2 += h[(size_t)s2 * HID_F + lane];
        a3 += h[(size_t)s3 * HID_F + lane];
    }
    for (; i < end; i++) a0 += h[(size_t)csr_src[i] * HID_F + lane];
    float v = ((a0 + a1) + (a2 + a3)) * norm_d[node] + b1[lane];
    v = fmaxf(v, 0.0f);
    x1s[(size_t)node * HID_F + lane] = v * norm_s[node];
}

// ---------------------------------------------------------------------------
// 8. GEMM2 (64 -> 16)
// ---------------------------------------------------------------------------
__global__ __launch_bounds__(256) void gemm2_kernel(const float* __restrict__ x,
                                                    const float* __restrict__ W,
                                                    float* __restrict__ h2, int N) {
    __shared__ float sW[HID_F * OUT_F];
    __shared__ float sx[32][HID_F + 1];
    for (int i = threadIdx.x; i < HID_F * OUT_F; i += 256) sW[i] = W[i];
    int row0 = blockIdx.x * 32;
    for (int i = threadIdx.x; i < 32 * HID_F; i += 256) {
        int r = i >> 6, k = i & 63;
        int gr = row0 + r;
        sx[r][k] = (gr < N) ? x[(size_t)gr * HID_F + k] : 0.0f;
    }
    __syncthreads();
    int col  = threadIdx.x & 15;
    int rgrp = threadIdx.x >> 4;
    for (int rr = 0; rr < 2; rr++) {
        int r = rgrp * 2 + rr;
        float acc = 0.0f;
        #pragma unroll 8
        for (int k = 0; k < HID_F; k++) acc += sx[r][k] * sW[k * OUT_F + col];
        int gr = row0 + r;
        if (gr < N) h2[(size_t)gr * OUT_F + col] = acc;
    }
}

// ---------------------------------------------------------------------------
// 9. CSR aggregation layer 2 (16 feats) + fused epilogue
// ---------------------------------------------------------------------------
__global__ __launch_bounds__(256) void agg2_kernel(const int* __restrict__ row_start,
                                                   const unsigned short* __restrict__ csr_src,
                                                   const float* __restrict__ h2,
                                                   const float* __restrict__ norm_d,
                                                   const float* __restrict__ b2,
                                                   float* __restrict__ out, int N) {
    int node = blockIdx.x * 4 + (threadIdx.x >> 6);
    if (node >= N) return;
    int lane = threadIdx.x & 63;
    int f = lane & 15;
    int j = lane >> 4;
    int beg = row_start[node], end = row_start[node + 1];
    float acc = 0.0f;
    for (int i = beg + j; i < end; i += 4)
        acc += h2[(size_t)csr_src[i] * OUT_F + f];
    acc += __shfl_xor(acc, 16);
    acc += __shfl_xor(acc, 32);
    if (j == 0)
        out[(size_t)node * OUT_F + f] = acc * norm_d[node] + b2[f];
}

extern "C" void kernel_launch(void* const* d_in, const int* in_sizes, int n_in,
                              void* d_out, int out_size, void* d_ws, size_t ws_size,
                              hipStream_t stream) {
    const float* feat = (const float*)d_in[0];
    const float* W1   = (const float*)d_in[1];
    const float* b1   = (const float*)d_in[2];
    const float* W2   = (const float*)d_in[3];
    const float* b2   = (const float*)d_in[4];
    const int*   src  = (const int*)d_in[5];
    const int*   dst  = (const int*)d_in[6];

    const int N   = in_sizes[0] / IN_F;       // 50000 (<= MAX_N)
    const int E   = in_sizes[5];              // 1.6M
    const int seg = (E + NSEG - 1) / NSEG;
    const int Wr  = (N + 1) >> 1;
    const int nchunks = (N + SCAN_CHUNK - 1) / SCAN_CHUNK;   // 49

    // ---- workspace layout (~36 MB) ----
    float* fws    = (float*)d_ws;
    float* norm_s = fws;                       // N
    float* norm_d = fws + N;                   // N
    float* h1     = fws + 2 * (size_t)N;       // N*64  (reused as h2: N*16)
    float* x1s    = h1 + (size_t)N * HID_F;    // N*64
    int*   iws    = (int*)(x1s + (size_t)N * HID_F);
    int*   deg_out   = iws;                    // N
    int*   row_start = iws + N;                // N+1 (counts, then scanned in place)
    int*   bsum      = iws + 2 * N + 1;        // nchunks (+pad to 1024)
    unsigned int* partial = (unsigned int*)(iws + 2 * N + 1 + 1024);        // NSEG*Wr
    unsigned short* csr_src = (unsigned short*)(partial + (size_t)NSEG * Wr); // E u16

    // graph build: LDS histograms (no global atomics, no memsets needed)
    hist_lds_kernel<<<NSEG, 1024, 0, stream>>>(src, partial, E, seg, Wr);
    reduce_prefix_kernel<<<(Wr + 255) / 256, 256, 0, stream>>>(partial, deg_out, Wr, N);
    hist_lds_kernel<<<NSEG, 1024, 0, stream>>>(dst, partial, E, seg, Wr);
    reduce_prefix_kernel<<<(Wr + 255) / 256, 256, 0, stream>>>(partial, row_start, Wr, N);
    norm_kernel<<<(N + 255) / 256, 256, 0, stream>>>(deg_out, row_start, norm_s, norm_d, N);

    // multi-block scan: counts -> exclusive row_start (in place), row_start[N]=E
    scan_local_kernel<<<nchunks, SCAN_BLOCK, 0, stream>>>(row_start, bsum, N);
    scan_bsum_kernel<<<1, 1024, 0, stream>>>(bsum, row_start + N, nchunks);
    scan_add_kernel<<<(N + 255) / 256, 256, 0, stream>>>(row_start, bsum, N);

    scatter_lds_kernel<<<NSEG, 1024, 0, stream>>>(src, dst, row_start, partial, csr_src, E, seg, Wr, N);

    // layer 1
    gemm1_kernel<<<(N + 15) / 16, 256, 0, stream>>>(feat, W1, norm_s, h1, N);
    agg1_kernel<<<(N + 3) / 4, 256, 0, stream>>>(row_start, csr_src, h1, norm_d, norm_s, b1, x1s, N);

    // layer 2 (h2 reuses h1 buffer)
    float* h2 = h1;
    gemm2_kernel<<<(N + 31) / 32, 256, 0, stream>>>(x1s, W2, h2, N);
    agg2_kernel<<<(N + 3) / 4, 256, 0, stream>>>(row_start, csr_src, h2, norm_d, b2, (float*)d_out, N);
}

// Round 8
// 319.586 us; speedup vs baseline: 2.3017x; 1.0306x over previous
//
#include <hip/hip_runtime.h>
#include <hip/hip_fp16.h>

#define IN_F  128
#define HID_F 64
#define OUT_F 16
#define MAX_N 50176          // max nodes supported by LDS tables (25088 u32 words = 100.4 KB)
#define HWORDS (MAX_N / 2)
#define NSEG  64             // edge segments (one block each in hist/scatter)

#define SCAN_ELEMS 4
#define SCAN_BLOCK 256
#define SCAN_CHUNK (SCAN_BLOCK * SCAN_ELEMS)   // 1024 elements per block

// ---------------------------------------------------------------------------
// 1. per-segment LDS histogram (packed u16 halfwords), no global atomics.
// ---------------------------------------------------------------------------
__global__ __launch_bounds__(1024) void hist_lds_kernel(const int* __restrict__ ids,
                                                        unsigned int* __restrict__ partial,
                                                        int E, int seg, int Wr) {
    __shared__ unsigned int cnt[HWORDS];
    int b = blockIdx.x;
    for (int w = threadIdx.x; w < Wr; w += 1024) cnt[w] = 0;
    __syncthreads();
    int lo = b * seg, hi = min(lo + seg, E);
    for (int e = lo + threadIdx.x; e < hi; e += 1024) {
        int d = ids[e];
        atomicAdd(&cnt[d >> 1], 1u << ((d & 1) * 16));   // LDS atomic
    }
    __syncthreads();
    for (int w = threadIdx.x; w < Wr; w += 1024)
        partial[(size_t)b * Wr + w] = cnt[w];
}

// ---------------------------------------------------------------------------
// 2. reduce partials -> per-node totals; rewrite partials in place as
//    per-(segment,node) EXCLUSIVE prefix (fits u16).
// ---------------------------------------------------------------------------
__global__ __launch_bounds__(256) void reduce_prefix_kernel(unsigned int* __restrict__ partial,
                                                            int* __restrict__ totals,
                                                            int Wr, int N) {
    int w = blockIdx.x * 256 + threadIdx.x;
    if (w >= Wr) return;
    unsigned int r0 = 0, r1 = 0;
    for (int b = 0; b < NSEG; b++) {
        size_t idx = (size_t)b * Wr + w;
        unsigned int v = partial[idx];
        partial[idx] = r0 | (r1 << 16);
        r0 += v & 0xFFFFu;
        r1 += v >> 16;
    }
    int d0 = 2 * w, d1 = 2 * w + 1;
    if (d0 < N) totals[d0] = (int)r0;
    if (d1 < N) totals[d1] = (int)r1;
}

// ---------------------------------------------------------------------------
// 3. norms from int degrees: norm = rsqrt(max(deg,1))
// ---------------------------------------------------------------------------
__global__ __launch_bounds__(256) void norm_kernel(const int* __restrict__ deg_out,
                                                   const int* __restrict__ cnt_in,
                                                   float* __restrict__ norm_s,
                                                   float* __restrict__ norm_d, int N) {
    int i = blockIdx.x * 256 + threadIdx.x;
    if (i < N) {
        norm_s[i] = rsqrtf(fmaxf((float)deg_out[i], 1.0f));
        norm_d[i] = rsqrtf(fmaxf((float)cnt_in[i], 1.0f));
    }
}

// ---------------------------------------------------------------------------
// 4a. multi-block scan phase 1: local exclusive scan per 1024-elem chunk
// ---------------------------------------------------------------------------
__global__ __launch_bounds__(SCAN_BLOCK) void scan_local_kernel(int* __restrict__ counts,
                                                                int* __restrict__ bsum, int N) {
    __shared__ int part[SCAN_BLOCK];
    int t = threadIdx.x;
    int base = blockIdx.x * SCAN_CHUNK + t * SCAN_ELEMS;
    int v[SCAN_ELEMS];
    int s = 0;
    #pragma unroll
    for (int k = 0; k < SCAN_ELEMS; k++) {
        int i = base + k;
        v[k] = (i < N) ? counts[i] : 0;
        s += v[k];
    }
    part[t] = s;
    __syncthreads();
    for (int off = 1; off < SCAN_BLOCK; off <<= 1) {
        int x = (t >= off) ? part[t - off] : 0;
        __syncthreads();
        part[t] += x;
        __syncthreads();
    }
    int run = (t > 0) ? part[t - 1] : 0;
    #pragma unroll
    for (int k = 0; k < SCAN_ELEMS; k++) {
        int i = base + k;
        if (i < N) counts[i] = run;
        run += v[k];
    }
    if (t == SCAN_BLOCK - 1) bsum[blockIdx.x] = part[SCAN_BLOCK - 1];
}

// ---------------------------------------------------------------------------
// 4b. scan phase 2: single tiny block scans chunk totals, writes rowN (=E)
// ---------------------------------------------------------------------------
__global__ __launch_bounds__(1024) void scan_bsum_kernel(int* __restrict__ bsum,
                                                         int* __restrict__ rowN, int nblocks) {
    __shared__ int part[1024];
    int t = threadIdx.x;
    int v = (t < nblocks) ? bsum[t] : 0;
    part[t] = v;
    __syncthreads();
    for (int off = 1; off < 1024; off <<= 1) {
        int x = (t >= off) ? part[t - off] : 0;
        __syncthreads();
        part[t] += x;
        __syncthreads();
    }
    if (t < nblocks) bsum[t] = part[t] - v;   // exclusive
    if (t == 1023) *rowN = part[1023];
}

// ---------------------------------------------------------------------------
// 4c. scan phase 3: add chunk offsets
// ---------------------------------------------------------------------------
__global__ __launch_bounds__(256) void scan_add_kernel(int* __restrict__ counts,
                                                       const int* __restrict__ bsum, int N) {
    int i = blockIdx.x * 256 + threadIdx.x;
    if (i < N) counts[i] += bsum[i / SCAN_CHUNK];
}

// ---------------------------------------------------------------------------
// 5. scatter via LDS cursors (no global atomics)
// ---------------------------------------------------------------------------
__global__ __launch_bounds__(1024) void scatter_lds_kernel(const int* __restrict__ src,
                                                           const int* __restrict__ dst,
                                                           const int* __restrict__ row_start,
                                                           const unsigned int* __restrict__ prefix,
                                                           unsigned short* __restrict__ csr_src,
                                                           int E, int seg, int Wr, int N) {
    __shared__ unsigned int pos[HWORDS];
    int b = blockIdx.x;
    int lo = b * seg, hi = min(lo + seg, E);
    for (int p = 0; p * HWORDS < N; p++) {
        int nlo = p * HWORDS, nhi = min(nlo + HWORDS, N);
        for (int d = nlo + threadIdx.x; d < nhi; d += 1024) {
            unsigned int word = prefix[(size_t)b * Wr + (d >> 1)];
            unsigned int base16 = (word >> ((d & 1) * 16)) & 0xFFFFu;
            pos[d - nlo] = (unsigned int)row_start[d] + base16;
        }
        __syncthreads();
        for (int e = lo + threadIdx.x; e < hi; e += 1024) {
            int d = dst[e];
            if (d >= nlo && d < nhi) {
                unsigned int q = atomicAdd(&pos[d - nlo], 1u);   // LDS atomic
                csr_src[q] = (unsigned short)src[e];
            }
        }
        __syncthreads();
    }
}

// ---------------------------------------------------------------------------
// 6. GEMM1 (128 -> 64), output stored fp16 (accumulate fp32)
// ---------------------------------------------------------------------------
__global__ __launch_bounds__(256) void gemm1_kernel(const float* __restrict__ x,
                                                    const float* __restrict__ W,
                                                    const float* __restrict__ norm_s,
                                                    __half* __restrict__ h, int N) {
    __shared__ float sW[IN_F * HID_F];   // 32 KB
    __shared__ float sx[16][IN_F];       // 8 KB
    for (int i = threadIdx.x; i < IN_F * HID_F; i += 256) sW[i] = W[i];
    int row0 = blockIdx.x * 16;
    for (int i = threadIdx.x; i < 16 * IN_F; i += 256) {
        int r = i / IN_F, k = i % IN_F;
        int gr = row0 + r;
        sx[r][k] = (gr < N) ? x[(size_t)gr * IN_F + k] * norm_s[gr] : 0.0f;
    }
    __syncthreads();
    int col   = threadIdx.x & 63;
    int rbase = (threadIdx.x >> 6) * 4;
    for (int rr = 0; rr < 4; rr++) {
        int r = rbase + rr;
        float acc = 0.0f;
        #pragma unroll 8
        for (int k = 0; k < IN_F; k++) acc += sx[r][k] * sW[k * HID_F + col];
        int gr = row0 + r;
        if (gr < N) h[(size_t)gr * HID_F + col] = __float2half(acc);
    }
}

// ---------------------------------------------------------------------------
// 7. CSR aggregation layer 1 (64 feats, fp16 gather) + fused epilogue
// ---------------------------------------------------------------------------
__global__ __launch_bounds__(256) void agg1_kernel(const int* __restrict__ row_start,
                                                   const unsigned short* __restrict__ csr_src,
                                                   const __half* __restrict__ h,
                                                   const float* __restrict__ norm_d,
                                                   const float* __restrict__ norm_s,
                                                   const float* __restrict__ b1,
                                                   float* __restrict__ x1s, int N) {
    int node = blockIdx.x * 4 + (threadIdx.x >> 6);
    if (node >= N) return;
    int lane = threadIdx.x & 63;
    int beg = row_start[node], end = row_start[node + 1];
    float a0 = 0.f, a1 = 0.f, a2 = 0.f, a3 = 0.f;
    int i = beg;
    for (; i + 3 < end; i += 4) {
        int s0 = (int)csr_src[i],     s1 = (int)csr_src[i + 1];
        int s2 = (int)csr_src[i + 2], s3 = (int)csr_src[i + 3];
        a0 += __half2float(h[(size_t)s0 * HID_F + lane]);
        a1 += __half2float(h[(size_t)s1 * HID_F + lane]);
        a2 += __half2float(h[(size_t)s2 * HID_F + lane]);
        a3 += __half2float(h[(size_t)s3 * HID_F + lane]);
    }
    for (; i < end; i++) a0 += __half2float(h[(size_t)csr_src[i] * HID_F + lane]);
    float v = ((a0 + a1) + (a2 + a3)) * norm_d[node] + b1[lane];
    v = fmaxf(v, 0.0f);
    x1s[(size_t)node * HID_F + lane] = v * norm_s[node];
}

// ---------------------------------------------------------------------------
// 8. GEMM2 (64 -> 16), output stored fp16
// ---------------------------------------------------------------------------
__global__ __launch_bounds__(256) void gemm2_kernel(const float* __restrict__ x,
                                                    const float* __restrict__ W,
                                                    __half* __restrict__ h2, int N) {
    __shared__ float sW[HID_F * OUT_F];
    __shared__ float sx[32][HID_F + 1];
    for (int i = threadIdx.x; i < HID_F * OUT_F; i += 256) sW[i] = W[i];
    int row0 = blockIdx.x * 32;
    for (int i = threadIdx.x; i < 32 * HID_F; i += 256) {
        int r = i >> 6, k = i & 63;
        int gr = row0 + r;
        sx[r][k] = (gr < N) ? x[(size_t)gr * HID_F + k] : 0.0f;
    }
    __syncthreads();
    int col  = threadIdx.x & 15;
    int rgrp = threadIdx.x >> 4;
    for (int rr = 0; rr < 2; rr++) {
        int r = rgrp * 2 + rr;
        float acc = 0.0f;
        #pragma unroll 8
        for (int k = 0; k < HID_F; k++) acc += sx[r][k] * sW[k * OUT_F + col];
        int gr = row0 + r;
        if (gr < N) h2[(size_t)gr * OUT_F + col] = __float2half(acc);
    }
}

// ---------------------------------------------------------------------------
// 9. CSR aggregation layer 2 (16 feats, fp16 gather) + fused epilogue
// ---------------------------------------------------------------------------
__global__ __launch_bounds__(256) void agg2_kernel(const int* __restrict__ row_start,
                                                   const unsigned short* __restrict__ csr_src,
                                                   const __half* __restrict__ h2,
                                                   const float* __restrict__ norm_d,
                                                   const float* __restrict__ b2,
                                                   float* __restrict__ out, int N) {
    int node = blockIdx.x * 4 + (threadIdx.x >> 6);
    if (node >= N) return;
    int lane = threadIdx.x & 63;
    int f = lane & 15;
    int j = lane >> 4;
    int beg = row_start[node], end = row_start[node + 1];
    float acc = 0.0f;
    for (int i = beg + j; i < end; i += 4)
        acc += __half2float(h2[(size_t)csr_src[i] * OUT_F + f]);
    acc += __shfl_xor(acc, 16);
    acc += __shfl_xor(acc, 32);
    if (j == 0)
        out[(size_t)node * OUT_F + f] = acc * norm_d[node] + b2[f];
}

extern "C" void kernel_launch(void* const* d_in, const int* in_sizes, int n_in,
                              void* d_out, int out_size, void* d_ws, size_t ws_size,
                              hipStream_t stream) {
    const float* feat = (const float*)d_in[0];
    const float* W1   = (const float*)d_in[1];
    const float* b1   = (const float*)d_in[2];
    const float* W2   = (const float*)d_in[3];
    const float* b2   = (const float*)d_in[4];
    const int*   src  = (const int*)d_in[5];
    const int*   dst  = (const int*)d_in[6];

    const int N   = in_sizes[0] / IN_F;       // 50000 (<= MAX_N)
    const int E   = in_sizes[5];              // 1.6M
    const int seg = (E + NSEG - 1) / NSEG;
    const int Wr  = (N + 1) >> 1;
    const int nchunks = (N + SCAN_CHUNK - 1) / SCAN_CHUNK;   // 49

    // ---- workspace layout ----
    float* fws    = (float*)d_ws;
    float* norm_s = fws;                       // N
    float* norm_d = fws + N;                   // N
    __half* h1    = (__half*)(fws + 2 * (size_t)N);          // N*64 halves (reused as h2: N*16 halves)
    float* x1s    = (float*)(h1 + (size_t)N * HID_F);        // N*64 floats
    int*   iws    = (int*)(x1s + (size_t)N * HID_F);
    int*   deg_out   = iws;                    // N
    int*   row_start = iws + N;                // N+1 (counts, then scanned in place)
    int*   bsum      = iws + 2 * N + 1;        // nchunks (+pad to 1024)
    unsigned int* partial = (unsigned int*)(iws + 2 * N + 1 + 1024);        // NSEG*Wr
    unsigned short* csr_src = (unsigned short*)(partial + (size_t)NSEG * Wr); // E u16

    // graph build: LDS histograms (no global atomics, no memsets needed)
    hist_lds_kernel<<<NSEG, 1024, 0, stream>>>(src, partial, E, seg, Wr);
    reduce_prefix_kernel<<<(Wr + 255) / 256, 256, 0, stream>>>(partial, deg_out, Wr, N);
    hist_lds_kernel<<<NSEG, 1024, 0, stream>>>(dst, partial, E, seg, Wr);
    reduce_prefix_kernel<<<(Wr + 255) / 256, 256, 0, stream>>>(partial, row_start, Wr, N);
    norm_kernel<<<(N + 255) / 256, 256, 0, stream>>>(deg_out, row_start, norm_s, norm_d, N);

    // multi-block scan: counts -> exclusive row_start (in place), row_start[N]=E
    scan_local_kernel<<<nchunks, SCAN_BLOCK, 0, stream>>>(row_start, bsum, N);
    scan_bsum_kernel<<<1, 1024, 0, stream>>>(bsum, row_start + N, nchunks);
    scan_add_kernel<<<(N + 255) / 256, 256, 0, stream>>>(row_start, bsum, N);

    scatter_lds_kernel<<<NSEG, 1024, 0, stream>>>(src, dst, row_start, partial, csr_src, E, seg, Wr, N);

    // layer 1
    gemm1_kernel<<<(N + 15) / 16, 256, 0, stream>>>(feat, W1, norm_s, h1, N);
    agg1_kernel<<<(N + 3) / 4, 256, 0, stream>>>(row_start, csr_src, h1, norm_d, norm_s, b1, x1s, N);

    // layer 2 (h2 reuses h1 buffer)
    __half* h2 = h1;
    gemm2_kernel<<<(N + 31) / 32, 256, 0, stream>>>(x1s, W2, h2, N);
    agg2_kernel<<<(N + 3) / 4, 256, 0, stream>>>(row_start, csr_src, h2, norm_d, b2, (float*)d_out, N);
}

// Round 9
// 291.823 us; speedup vs baseline: 2.5206x; 1.0951x over previous
//
#include <hip/hip_runtime.h>
#include <hip/hip_fp16.h>

#define IN_F  128
#define HID_F 64
#define OUT_F 16
#define MAX_N 50176          // max nodes supported by LDS tables (25088 u32 words = 100.4 KB)
#define HWORDS (MAX_N / 2)
#define NSEG  64             // edge segments (one block each in hist/scatter)

#define SCAN_ELEMS 4
#define SCAN_BLOCK 256
#define SCAN_CHUNK (SCAN_BLOCK * SCAN_ELEMS)   // 1024 elements per block

// ---------------------------------------------------------------------------
// 1. per-segment LDS histogram (packed u16 halfwords), no global atomics.
// ---------------------------------------------------------------------------
__global__ __launch_bounds__(1024) void hist_lds_kernel(const int* __restrict__ ids,
                                                        unsigned int* __restrict__ partial,
                                                        int E, int seg, int Wr) {
    __shared__ unsigned int cnt[HWORDS];
    int b = blockIdx.x;
    for (int w = threadIdx.x; w < Wr; w += 1024) cnt[w] = 0;
    __syncthreads();
    int lo = b * seg, hi = min(lo + seg, E);
    for (int e = lo + threadIdx.x; e < hi; e += 1024) {
        int d = ids[e];
        atomicAdd(&cnt[d >> 1], 1u << ((d & 1) * 16));   // LDS atomic
    }
    __syncthreads();
    for (int w = threadIdx.x; w < Wr; w += 1024)
        partial[(size_t)b * Wr + w] = cnt[w];
}

// ---------------------------------------------------------------------------
// 2. reduce partials -> per-node totals; rewrite partials in place as
//    per-(segment,node) EXCLUSIVE prefix (fits u16).
// ---------------------------------------------------------------------------
__global__ __launch_bounds__(256) void reduce_prefix_kernel(unsigned int* __restrict__ partial,
                                                            int* __restrict__ totals,
                                                            int Wr, int N) {
    int w = blockIdx.x * 256 + threadIdx.x;
    if (w >= Wr) return;
    unsigned int r0 = 0, r1 = 0;
    for (int b = 0; b < NSEG; b++) {
        size_t idx = (size_t)b * Wr + w;
        unsigned int v = partial[idx];
        partial[idx] = r0 | (r1 << 16);
        r0 += v & 0xFFFFu;
        r1 += v >> 16;
    }
    int d0 = 2 * w, d1 = 2 * w + 1;
    if (d0 < N) totals[d0] = (int)r0;
    if (d1 < N) totals[d1] = (int)r1;
}

// ---------------------------------------------------------------------------
// 3. norms from int degrees: norm = rsqrt(max(deg,1))
// ---------------------------------------------------------------------------
__global__ __launch_bounds__(256) void norm_kernel(const int* __restrict__ deg_out,
                                                   const int* __restrict__ cnt_in,
                                                   float* __restrict__ norm_s,
                                                   float* __restrict__ norm_d, int N) {
    int i = blockIdx.x * 256 + threadIdx.x;
    if (i < N) {
        norm_s[i] = rsqrtf(fmaxf((float)deg_out[i], 1.0f));
        norm_d[i] = rsqrtf(fmaxf((float)cnt_in[i], 1.0f));
    }
}

// ---------------------------------------------------------------------------
// 4a. multi-block scan phase 1: local exclusive scan per 1024-elem chunk
// ---------------------------------------------------------------------------
__global__ __launch_bounds__(SCAN_BLOCK) void scan_local_kernel(int* __restrict__ counts,
                                                                int* __restrict__ bsum, int N) {
    __shared__ int part[SCAN_BLOCK];
    int t = threadIdx.x;
    int base = blockIdx.x * SCAN_CHUNK + t * SCAN_ELEMS;
    int v[SCAN_ELEMS];
    int s = 0;
    #pragma unroll
    for (int k = 0; k < SCAN_ELEMS; k++) {
        int i = base + k;
        v[k] = (i < N) ? counts[i] : 0;
        s += v[k];
    }
    part[t] = s;
    __syncthreads();
    for (int off = 1; off < SCAN_BLOCK; off <<= 1) {
        int x = (t >= off) ? part[t - off] : 0;
        __syncthreads();
        part[t] += x;
        __syncthreads();
    }
    int run = (t > 0) ? part[t - 1] : 0;
    #pragma unroll
    for (int k = 0; k < SCAN_ELEMS; k++) {
        int i = base + k;
        if (i < N) counts[i] = run;
        run += v[k];
    }
    if (t == SCAN_BLOCK - 1) bsum[blockIdx.x] = part[SCAN_BLOCK - 1];
}

// ---------------------------------------------------------------------------
// 4b. scan phase 2: single tiny block scans chunk totals, writes rowN (=E)
// ---------------------------------------------------------------------------
__global__ __launch_bounds__(1024) void scan_bsum_kernel(int* __restrict__ bsum,
                                                         int* __restrict__ rowN, int nblocks) {
    __shared__ int part[1024];
    int t = threadIdx.x;
    int v = (t < nblocks) ? bsum[t] : 0;
    part[t] = v;
    __syncthreads();
    for (int off = 1; off < 1024; off <<= 1) {
        int x = (t >= off) ? part[t - off] : 0;
        __syncthreads();
        part[t] += x;
        __syncthreads();
    }
    if (t < nblocks) bsum[t] = part[t] - v;   // exclusive
    if (t == 1023) *rowN = part[1023];
}

// ---------------------------------------------------------------------------
// 4c. scan phase 3: add chunk offsets
// ---------------------------------------------------------------------------
__global__ __launch_bounds__(256) void scan_add_kernel(int* __restrict__ counts,
                                                       const int* __restrict__ bsum, int N) {
    int i = blockIdx.x * 256 + threadIdx.x;
    if (i < N) counts[i] += bsum[i / SCAN_CHUNK];
}

// ---------------------------------------------------------------------------
// 5. scatter via LDS cursors (no global atomics)
// ---------------------------------------------------------------------------
__global__ __launch_bounds__(1024) void scatter_lds_kernel(const int* __restrict__ src,
                                                           const int* __restrict__ dst,
                                                           const int* __restrict__ row_start,
                                                           const unsigned int* __restrict__ prefix,
                                                           unsigned short* __restrict__ csr_src,
                                                           int E, int seg, int Wr, int N) {
    __shared__ unsigned int pos[HWORDS];
    int b = blockIdx.x;
    int lo = b * seg, hi = min(lo + seg, E);
    for (int p = 0; p * HWORDS < N; p++) {
        int nlo = p * HWORDS, nhi = min(nlo + HWORDS, N);
        for (int d = nlo + threadIdx.x; d < nhi; d += 1024) {
            unsigned int word = prefix[(size_t)b * Wr + (d >> 1)];
            unsigned int base16 = (word >> ((d & 1) * 16)) & 0xFFFFu;
            pos[d - nlo] = (unsigned int)row_start[d] + base16;
        }
        __syncthreads();
        for (int e = lo + threadIdx.x; e < hi; e += 1024) {
            int d = dst[e];
            if (d >= nlo && d < nhi) {
                unsigned int q = atomicAdd(&pos[d - nlo], 1u);   // LDS atomic
                csr_src[q] = (unsigned short)src[e];
            }
        }
        __syncthreads();
    }
}

// ---------------------------------------------------------------------------
// 6. GEMM1 (128 -> 64), output stored fp16 (accumulate fp32)
// ---------------------------------------------------------------------------
__global__ __launch_bounds__(256) void gemm1_kernel(const float* __restrict__ x,
                                                    const float* __restrict__ W,
                                                    const float* __restrict__ norm_s,
                                                    __half* __restrict__ h, int N) {
    __shared__ float sW[IN_F * HID_F];   // 32 KB
    __shared__ float sx[16][IN_F];       // 8 KB
    for (int i = threadIdx.x; i < IN_F * HID_F; i += 256) sW[i] = W[i];
    int row0 = blockIdx.x * 16;
    for (int i = threadIdx.x; i < 16 * IN_F; i += 256) {
        int r = i / IN_F, k = i % IN_F;
        int gr = row0 + r;
        sx[r][k] = (gr < N) ? x[(size_t)gr * IN_F + k] * norm_s[gr] : 0.0f;
    }
    __syncthreads();
    int col   = threadIdx.x & 63;
    int rbase = (threadIdx.x >> 6) * 4;
    for (int rr = 0; rr < 4; rr++) {
        int r = rbase + rr;
        float acc = 0.0f;
        #pragma unroll 8
        for (int k = 0; k < IN_F; k++) acc += sx[r][k] * sW[k * HID_F + col];
        int gr = row0 + r;
        if (gr < N) h[(size_t)gr * HID_F + col] = __float2half(acc);
    }
}

// ---------------------------------------------------------------------------
// 7. CSR aggregation layer 1: wide gather — lane loads half4 (8B), 16 lanes
//    per 128-B row, 4 edges per VMEM instruction. slot = lane>>4 owns edges
//    i === slot (mod 4); cross-slot combine via shfl_xor; float4 store.
// ---------------------------------------------------------------------------
__global__ __launch_bounds__(256) void agg1_kernel(const int* __restrict__ row_start,
                                                   const unsigned short* __restrict__ csr_src,
                                                   const __half* __restrict__ h,
                                                   const float* __restrict__ norm_d,
                                                   const float* __restrict__ norm_s,
                                                   const float* __restrict__ b1,
                                                   float* __restrict__ x1s, int N) {
    int node = blockIdx.x * 4 + (threadIdx.x >> 6);
    if (node >= N) return;
    int lane = threadIdx.x & 63;
    int slot = lane >> 4;        // 0..3: which edge in the group of 4
    int fq   = lane & 15;        // feature quad: features fq*4 .. fq*4+3
    int beg = row_start[node], end = row_start[node + 1];

    float ax = 0.f, ay = 0.f, az = 0.f, aw = 0.f;

    #define AGG1_BODY(I) {                                                   \
        int sidx = (int)csr_src[(I)];                                        \
        const uint2* p = (const uint2*)(h + (size_t)sidx * HID_F + fq * 4);  \
        uint2 u = *p;                                                        \
        __half2 p0 = *(__half2*)&u.x, p1 = *(__half2*)&u.y;                  \
        float2 f0 = __half22float2(p0), f1 = __half22float2(p1);             \
        ax += f0.x; ay += f0.y; az += f1.x; aw += f1.y; }

    int i = beg + slot;
    for (; i + 4 < end; i += 8) { AGG1_BODY(i); AGG1_BODY(i + 4); }
    if (i < end) AGG1_BODY(i);
    #undef AGG1_BODY

    // combine the 4 slots (partials live at lanes fq, fq+16, fq+32, fq+48)
    ax += __shfl_xor(ax, 16); ay += __shfl_xor(ay, 16);
    az += __shfl_xor(az, 16); aw += __shfl_xor(aw, 16);
    ax += __shfl_xor(ax, 32); ay += __shfl_xor(ay, 32);
    az += __shfl_xor(az, 32); aw += __shfl_xor(aw, 32);

    if (slot == 0) {
        float nd = norm_d[node], ns = norm_s[node];
        const float4 b = *(const float4*)(b1 + fq * 4);
        float4 v;
        v.x = fmaxf(ax * nd + b.x, 0.f) * ns;
        v.y = fmaxf(ay * nd + b.y, 0.f) * ns;
        v.z = fmaxf(az * nd + b.z, 0.f) * ns;
        v.w = fmaxf(aw * nd + b.w, 0.f) * ns;
        *(float4*)(x1s + (size_t)node * HID_F + fq * 4) = v;
    }
}

// ---------------------------------------------------------------------------
// 8. GEMM2 (64 -> 16), output stored fp16
// ---------------------------------------------------------------------------
__global__ __launch_bounds__(256) void gemm2_kernel(const float* __restrict__ x,
                                                    const float* __restrict__ W,
                                                    __half* __restrict__ h2, int N) {
    __shared__ float sW[HID_F * OUT_F];
    __shared__ float sx[32][HID_F + 1];
    for (int i = threadIdx.x; i < HID_F * OUT_F; i += 256) sW[i] = W[i];
    int row0 = blockIdx.x * 32;
    for (int i = threadIdx.x; i < 32 * HID_F; i += 256) {
        int r = i >> 6, k = i & 63;
        int gr = row0 + r;
        sx[r][k] = (gr < N) ? x[(size_t)gr * HID_F + k] : 0.0f;
    }
    __syncthreads();
    int col  = threadIdx.x & 15;
    int rgrp = threadIdx.x >> 4;
    for (int rr = 0; rr < 2; rr++) {
        int r = rgrp * 2 + rr;
        float acc = 0.0f;
        #pragma unroll 8
        for (int k = 0; k < HID_F; k++) acc += sx[r][k] * sW[k * OUT_F + col];
        int gr = row0 + r;
        if (gr < N) h2[(size_t)gr * OUT_F + col] = __float2half(acc);
    }
}

// ---------------------------------------------------------------------------
// 9. CSR aggregation layer 2: lane loads half2 (4B), 8 lanes per 32-B row,
//    8 edges per VMEM instruction; 3-step shfl_xor combine; float2 store.
// ---------------------------------------------------------------------------
__global__ __launch_bounds__(256) void agg2_kernel(const int* __restrict__ row_start,
                                                   const unsigned short* __restrict__ csr_src,
                                                   const __half* __restrict__ h2,
                                                   const float* __restrict__ norm_d,
                                                   const float* __restrict__ b2,
                                                   float* __restrict__ out, int N) {
    int node = blockIdx.x * 4 + (threadIdx.x >> 6);
    if (node >= N) return;
    int lane = threadIdx.x & 63;
    int slot = lane >> 3;        // 0..7: which edge in the group of 8
    int fh   = lane & 7;         // feature pair: features fh*2, fh*2+1
    int beg = row_start[node], end = row_start[node + 1];

    float ax = 0.f, ay = 0.f;

    #define AGG2_BODY(I) {                                                   \
        int sidx = (int)csr_src[(I)];                                        \
        __half2 p = *(const __half2*)(h2 + (size_t)sidx * OUT_F + fh * 2);   \
        float2 f = __half22float2(p);                                        \
        ax += f.x; ay += f.y; }

    int i = beg + slot;
    for (; i + 8 < end; i += 16) { AGG2_BODY(i); AGG2_BODY(i + 8); }
    if (i < end) AGG2_BODY(i);
    #undef AGG2_BODY

    ax += __shfl_xor(ax, 8);  ay += __shfl_xor(ay, 8);
    ax += __shfl_xor(ax, 16); ay += __shfl_xor(ay, 16);
    ax += __shfl_xor(ax, 32); ay += __shfl_xor(ay, 32);

    if (slot == 0) {
        float nd = norm_d[node];
        float2 v;
        v.x = ax * nd + b2[fh * 2];
        v.y = ay * nd + b2[fh * 2 + 1];
        *(float2*)(out + (size_t)node * OUT_F + fh * 2) = v;
    }
}

extern "C" void kernel_launch(void* const* d_in, const int* in_sizes, int n_in,
                              void* d_out, int out_size, void* d_ws, size_t ws_size,
                              hipStream_t stream) {
    const float* feat = (const float*)d_in[0];
    const float* W1   = (const float*)d_in[1];
    const float* b1   = (const float*)d_in[2];
    const float* W2   = (const float*)d_in[3];
    const float* b2   = (const float*)d_in[4];
    const int*   src  = (const int*)d_in[5];
    const int*   dst  = (const int*)d_in[6];

    const int N   = in_sizes[0] / IN_F;       // 50000 (<= MAX_N)
    const int E   = in_sizes[5];              // 1.6M
    const int seg = (E + NSEG - 1) / NSEG;
    const int Wr  = (N + 1) >> 1;
    const int nchunks = (N + SCAN_CHUNK - 1) / SCAN_CHUNK;   // 49

    // ---- workspace layout ----
    float* fws    = (float*)d_ws;
    float* norm_s = fws;                       // N
    float* norm_d = fws + N;                   // N
    __half* h1    = (__half*)(fws + 2 * (size_t)N);          // N*64 halves (reused as h2: N*16 halves)
    float* x1s    = (float*)(h1 + (size_t)N * HID_F);        // N*64 floats
    int*   iws    = (int*)(x1s + (size_t)N * HID_F);
    int*   deg_out   = iws;                    // N
    int*   row_start = iws + N;                // N+1 (counts, then scanned in place)
    int*   bsum      = iws + 2 * N + 1;        // nchunks (+pad to 1024)
    unsigned int* partial = (unsigned int*)(iws + 2 * N + 1 + 1024);        // NSEG*Wr
    unsigned short* csr_src = (unsigned short*)(partial + (size_t)NSEG * Wr); // E u16

    // graph build: LDS histograms (no global atomics, no memsets needed)
    hist_lds_kernel<<<NSEG, 1024, 0, stream>>>(src, partial, E, seg, Wr);
    reduce_prefix_kernel<<<(Wr + 255) / 256, 256, 0, stream>>>(partial, deg_out, Wr, N);
    hist_lds_kernel<<<NSEG, 1024, 0, stream>>>(dst, partial, E, seg, Wr);
    reduce_prefix_kernel<<<(Wr + 255) / 256, 256, 0, stream>>>(partial, row_start, Wr, N);
    norm_kernel<<<(N + 255) / 256, 256, 0, stream>>>(deg_out, row_start, norm_s, norm_d, N);

    // multi-block scan: counts -> exclusive row_start (in place), row_start[N]=E
    scan_local_kernel<<<nchunks, SCAN_BLOCK, 0, stream>>>(row_start, bsum, N);
    scan_bsum_kernel<<<1, 1024, 0, stream>>>(bsum, row_start + N, nchunks);
    scan_add_kernel<<<(N + 255) / 256, 256, 0, stream>>>(row_start, bsum, N);

    scatter_lds_kernel<<<NSEG, 1024, 0, stream>>>(src, dst, row_start, partial, csr_src, E, seg, Wr, N);

    // layer 1
    gemm1_kernel<<<(N + 15) / 16, 256, 0, stream>>>(feat, W1, norm_s, h1, N);
    agg1_kernel<<<(N + 3) / 4, 256, 0, stream>>>(row_start, csr_src, h1, norm_d, norm_s, b1, x1s, N);

    // layer 2 (h2 reuses h1 buffer)
    __half* h2 = h1;
    gemm2_kernel<<<(N + 31) / 32, 256, 0, stream>>>(x1s, W2, h2, N);
    agg2_kernel<<<(N + 3) / 4, 256, 0, stream>>>(row_start, csr_src, h2, norm_d, b2, (float*)d_out, N);
}

// Round 10
// 255.851 us; speedup vs baseline: 2.8750x; 1.1406x over previous
//
#include <hip/hip_runtime.h>
#include <hip/hip_fp16.h>

#define IN_F  128
#define HID_F 64
#define OUT_F 16
#define MAX_N 50176          // max nodes supported by LDS tables (25088 u32 words = 100.4 KB)
#define HWORDS (MAX_N / 2)
#define NSEG  64             // edge segments (one block each in hist/scatter)

#define SCAN_ELEMS 4
#define SCAN_BLOCK 256
#define SCAN_CHUNK (SCAN_BLOCK * SCAN_ELEMS)   // 1024 elements per block

#define LSTR 136             // LDS row stride in halves (128 + 8 pad: 2-way-free banks, 16B aligned)

typedef __attribute__((ext_vector_type(8))) _Float16 half8;
typedef __attribute__((ext_vector_type(4))) _Float16 half4v;
typedef __attribute__((ext_vector_type(4))) float    floatx4;

// ---------------------------------------------------------------------------
// 1. per-segment LDS histogram (packed u16 halfwords), no global atomics.
// ---------------------------------------------------------------------------
__global__ __launch_bounds__(1024) void hist_lds_kernel(const int* __restrict__ ids,
                                                        unsigned int* __restrict__ partial,
                                                        int E, int seg, int Wr) {
    __shared__ unsigned int cnt[HWORDS];
    int b = blockIdx.x;
    for (int w = threadIdx.x; w < Wr; w += 1024) cnt[w] = 0;
    __syncthreads();
    int lo = b * seg, hi = min(lo + seg, E);
    for (int e = lo + threadIdx.x; e < hi; e += 1024) {
        int d = ids[e];
        atomicAdd(&cnt[d >> 1], 1u << ((d & 1) * 16));   // LDS atomic
    }
    __syncthreads();
    for (int w = threadIdx.x; w < Wr; w += 1024)
        partial[(size_t)b * Wr + w] = cnt[w];
}

// ---------------------------------------------------------------------------
// 2. reduce partials -> per-node totals; rewrite partials in place as
//    per-(segment,node) EXCLUSIVE prefix (fits u16).
// ---------------------------------------------------------------------------
__global__ __launch_bounds__(256) void reduce_prefix_kernel(unsigned int* __restrict__ partial,
                                                            int* __restrict__ totals,
                                                            int Wr, int N) {
    int w = blockIdx.x * 256 + threadIdx.x;
    if (w >= Wr) return;
    unsigned int r0 = 0, r1 = 0;
    for (int b = 0; b < NSEG; b++) {
        size_t idx = (size_t)b * Wr + w;
        unsigned int v = partial[idx];
        partial[idx] = r0 | (r1 << 16);
        r0 += v & 0xFFFFu;
        r1 += v >> 16;
    }
    int d0 = 2 * w, d1 = 2 * w + 1;
    if (d0 < N) totals[d0] = (int)r0;
    if (d1 < N) totals[d1] = (int)r1;
}

// ---------------------------------------------------------------------------
// 3. norms from int degrees: norm = rsqrt(max(deg,1))
// ---------------------------------------------------------------------------
__global__ __launch_bounds__(256) void norm_kernel(const int* __restrict__ deg_out,
                                                   const int* __restrict__ cnt_in,
                                                   float* __restrict__ norm_s,
                                                   float* __restrict__ norm_d, int N) {
    int i = blockIdx.x * 256 + threadIdx.x;
    if (i < N) {
        norm_s[i] = rsqrtf(fmaxf((float)deg_out[i], 1.0f));
        norm_d[i] = rsqrtf(fmaxf((float)cnt_in[i], 1.0f));
    }
}

// ---------------------------------------------------------------------------
// 4a. multi-block scan phase 1: local exclusive scan per 1024-elem chunk
// ---------------------------------------------------------------------------
__global__ __launch_bounds__(SCAN_BLOCK) void scan_local_kernel(int* __restrict__ counts,
                                                                int* __restrict__ bsum, int N) {
    __shared__ int part[SCAN_BLOCK];
    int t = threadIdx.x;
    int base = blockIdx.x * SCAN_CHUNK + t * SCAN_ELEMS;
    int v[SCAN_ELEMS];
    int s = 0;
    #pragma unroll
    for (int k = 0; k < SCAN_ELEMS; k++) {
        int i = base + k;
        v[k] = (i < N) ? counts[i] : 0;
        s += v[k];
    }
    part[t] = s;
    __syncthreads();
    for (int off = 1; off < SCAN_BLOCK; off <<= 1) {
        int x = (t >= off) ? part[t - off] : 0;
        __syncthreads();
        part[t] += x;
        __syncthreads();
    }
    int run = (t > 0) ? part[t - 1] : 0;
    #pragma unroll
    for (int k = 0; k < SCAN_ELEMS; k++) {
        int i = base + k;
        if (i < N) counts[i] = run;
        run += v[k];
    }
    if (t == SCAN_BLOCK - 1) bsum[blockIdx.x] = part[SCAN_BLOCK - 1];
}

// ---------------------------------------------------------------------------
// 4b. scan phase 2: single tiny block scans chunk totals, writes rowN (=E)
// ---------------------------------------------------------------------------
__global__ __launch_bounds__(1024) void scan_bsum_kernel(int* __restrict__ bsum,
                                                         int* __restrict__ rowN, int nblocks) {
    __shared__ int part[1024];
    int t = threadIdx.x;
    int v = (t < nblocks) ? bsum[t] : 0;
    part[t] = v;
    __syncthreads();
    for (int off = 1; off < 1024; off <<= 1) {
        int x = (t >= off) ? part[t - off] : 0;
        __syncthreads();
        part[t] += x;
        __syncthreads();
    }
    if (t < nblocks) bsum[t] = part[t] - v;   // exclusive
    if (t == 1023) *rowN = part[1023];
}

// ---------------------------------------------------------------------------
// 4c. scan phase 3: add chunk offsets
// ---------------------------------------------------------------------------
__global__ __launch_bounds__(256) void scan_add_kernel(int* __restrict__ counts,
                                                       const int* __restrict__ bsum, int N) {
    int i = blockIdx.x * 256 + threadIdx.x;
    if (i < N) counts[i] += bsum[i / SCAN_CHUNK];
}

// ---------------------------------------------------------------------------
// 5. scatter via LDS cursors (no global atomics)
// ---------------------------------------------------------------------------
__global__ __launch_bounds__(1024) void scatter_lds_kernel(const int* __restrict__ src,
                                                           const int* __restrict__ dst,
                                                           const int* __restrict__ row_start,
                                                           const unsigned int* __restrict__ prefix,
                                                           unsigned short* __restrict__ csr_src,
                                                           int E, int seg, int Wr, int N) {
    __shared__ unsigned int pos[HWORDS];
    int b = blockIdx.x;
    int lo = b * seg, hi = min(lo + seg, E);
    for (int p = 0; p * HWORDS < N; p++) {
        int nlo = p * HWORDS, nhi = min(nlo + HWORDS, N);
        for (int d = nlo + threadIdx.x; d < nhi; d += 1024) {
            unsigned int word = prefix[(size_t)b * Wr + (d >> 1)];
            unsigned int base16 = (word >> ((d & 1) * 16)) & 0xFFFFu;
            pos[d - nlo] = (unsigned int)row_start[d] + base16;
        }
        __syncthreads();
        for (int e = lo + threadIdx.x; e < hi; e += 1024) {
            int d = dst[e];
            if (d >= nlo && d < nhi) {
                unsigned int q = atomicAdd(&pos[d - nlo], 1u);   // LDS atomic
                csr_src[q] = (unsigned short)src[e];
            }
        }
        __syncthreads();
    }
}

// ---------------------------------------------------------------------------
// 6. GEMM1 via MFMA f32_16x16x32_f16: 64 rows/block, fp16 staged inputs,
//    fp32 accumulate, fp16 h output. A[m=lane&15][k=quad*8+j],
//    B[k=quad*8+j][n=lane&15], D col=lane&15 row=quad*4+reg (m89-verified).
// ---------------------------------------------------------------------------
__global__ __launch_bounds__(256) void gemm1_kernel(const float* __restrict__ x,
                                                    const float* __restrict__ W,
                                                    const float* __restrict__ norm_s,
                                                    __half* __restrict__ h, int N) {
    __shared__ _Float16 sx[64 * LSTR];   // 64 rows x 128 k (padded)
    __shared__ _Float16 sw[64 * LSTR];   // 64 n x 128 k (W transposed, padded)
    int t = threadIdx.x;
    int row0 = blockIdx.x * 64;

    // stage W transposed: sw[n*LSTR + k] = W[k*64 + n]
    for (int i = t; i < IN_F * 16; i += 256) {          // i over (k, n-quad)
        int k = i >> 4, n4 = (i & 15) * 4;
        float4 w4 = *(const float4*)(W + (size_t)k * HID_F + n4);
        sw[(n4 + 0) * LSTR + k] = (_Float16)w4.x;
        sw[(n4 + 1) * LSTR + k] = (_Float16)w4.y;
        sw[(n4 + 2) * LSTR + k] = (_Float16)w4.z;
        sw[(n4 + 3) * LSTR + k] = (_Float16)w4.w;
    }
    // stage x * norm_s as fp16: 64 rows x 128 k
    for (int i = t; i < 64 * 32; i += 256) {            // i over (row, k-quad)
        int r = i >> 5, k4 = (i & 31) * 4;
        int gr = row0 + r;
        half4v hv = {0, 0, 0, 0};
        if (gr < N) {
            float4 v = *(const float4*)(x + (size_t)gr * IN_F + k4);
            float ns = norm_s[gr];
            hv.x = (_Float16)(v.x * ns); hv.y = (_Float16)(v.y * ns);
            hv.z = (_Float16)(v.z * ns); hv.w = (_Float16)(v.w * ns);
        }
        *(half4v*)(sx + r * LSTR + k4) = hv;
    }
    __syncthreads();

    int wave = t >> 6, lane = t & 63;
    int m = lane & 15, quad = lane >> 4;
    int rbase = wave * 16;

    floatx4 acc[4] = {{0,0,0,0}, {0,0,0,0}, {0,0,0,0}, {0,0,0,0}};
    #pragma unroll
    for (int ks = 0; ks < 4; ks++) {
        half8 av = *(half8*)(sx + (rbase + m) * LSTR + ks * 32 + quad * 8);
        #pragma unroll
        for (int ct = 0; ct < 4; ct++) {
            half8 bv = *(half8*)(sw + (ct * 16 + m) * LSTR + ks * 32 + quad * 8);
            acc[ct] = __builtin_amdgcn_mfma_f32_16x16x32_f16(av, bv, acc[ct], 0, 0, 0);
        }
    }
    #pragma unroll
    for (int ct = 0; ct < 4; ct++) {
        #pragma unroll
        for (int reg = 0; reg < 4; reg++) {
            int gr = row0 + rbase + quad * 4 + reg;
            if (gr < N) h[(size_t)gr * HID_F + ct * 16 + m] = __float2half(acc[ct][reg]);
        }
    }
}

// ---------------------------------------------------------------------------
// 7. CSR aggregation layer 1: wide gather — lane loads half4 (8B), 16 lanes
//    per 128-B row, 4 edges per VMEM instruction; shfl_xor combine.
// ---------------------------------------------------------------------------
__global__ __launch_bounds__(256) void agg1_kernel(const int* __restrict__ row_start,
                                                   const unsigned short* __restrict__ csr_src,
                                                   const __half* __restrict__ h,
                                                   const float* __restrict__ norm_d,
                                                   const float* __restrict__ norm_s,
                                                   const float* __restrict__ b1,
                                                   float* __restrict__ x1s, int N) {
    int node = blockIdx.x * 4 + (threadIdx.x >> 6);
    if (node >= N) return;
    int lane = threadIdx.x & 63;
    int slot = lane >> 4;        // 0..3: which edge in the group of 4
    int fq   = lane & 15;        // feature quad: features fq*4 .. fq*4+3
    int beg = row_start[node], end = row_start[node + 1];

    float ax = 0.f, ay = 0.f, az = 0.f, aw = 0.f;

    #define AGG1_BODY(I) {                                                   \
        int sidx = (int)csr_src[(I)];                                        \
        const uint2* p = (const uint2*)(h + (size_t)sidx * HID_F + fq * 4);  \
        uint2 u = *p;                                                        \
        __half2 p0 = *(__half2*)&u.x, p1 = *(__half2*)&u.y;                  \
        float2 f0 = __half22float2(p0), f1 = __half22float2(p1);             \
        ax += f0.x; ay += f0.y; az += f1.x; aw += f1.y; }

    int i = beg + slot;
    for (; i + 4 < end; i += 8) { AGG1_BODY(i); AGG1_BODY(i + 4); }
    if (i < end) AGG1_BODY(i);
    #undef AGG1_BODY

    ax += __shfl_xor(ax, 16); ay += __shfl_xor(ay, 16);
    az += __shfl_xor(az, 16); aw += __shfl_xor(aw, 16);
    ax += __shfl_xor(ax, 32); ay += __shfl_xor(ay, 32);
    az += __shfl_xor(az, 32); aw += __shfl_xor(aw, 32);

    if (slot == 0) {
        float nd = norm_d[node], ns = norm_s[node];
        const float4 b = *(const float4*)(b1 + fq * 4);
        float4 v;
        v.x = fmaxf(ax * nd + b.x, 0.f) * ns;
        v.y = fmaxf(ay * nd + b.y, 0.f) * ns;
        v.z = fmaxf(az * nd + b.z, 0.f) * ns;
        v.w = fmaxf(aw * nd + b.w, 0.f) * ns;
        *(float4*)(x1s + (size_t)node * HID_F + fq * 4) = v;
    }
}

// ---------------------------------------------------------------------------
// 8. GEMM2 (64 -> 16), output stored fp16
// ---------------------------------------------------------------------------
__global__ __launch_bounds__(256) void gemm2_kernel(const float* __restrict__ x,
                                                    const float* __restrict__ W,
                                                    __half* __restrict__ h2, int N) {
    __shared__ float sW[HID_F * OUT_F];
    __shared__ float sx[32][HID_F + 1];
    for (int i = threadIdx.x; i < HID_F * OUT_F; i += 256) sW[i] = W[i];
    int row0 = blockIdx.x * 32;
    for (int i = threadIdx.x; i < 32 * HID_F; i += 256) {
        int r = i >> 6, k = i & 63;
        int gr = row0 + r;
        sx[r][k] = (gr < N) ? x[(size_t)gr * HID_F + k] : 0.0f;
    }
    __syncthreads();
    int col  = threadIdx.x & 15;
    int rgrp = threadIdx.x >> 4;
    for (int rr = 0; rr < 2; rr++) {
        int r = rgrp * 2 + rr;
        float acc = 0.0f;
        #pragma unroll 8
        for (int k = 0; k < HID_F; k++) acc += sx[r][k] * sW[k * OUT_F + col];
        int gr = row0 + r;
        if (gr < N) h2[(size_t)gr * OUT_F + col] = __float2half(acc);
    }
}

// ---------------------------------------------------------------------------
// 9. CSR aggregation layer 2: lane loads half2 (4B), 8 lanes per 32-B row,
//    8 edges per VMEM instruction; 3-step shfl_xor combine; float2 store.
// ---------------------------------------------------------------------------
__global__ __launch_bounds__(256) void agg2_kernel(const int* __restrict__ row_start,
                                                   const unsigned short* __restrict__ csr_src,
                                                   const __half* __restrict__ h2,
                                                   const float* __restrict__ norm_d,
                                                   const float* __restrict__ b2,
                                                   float* __restrict__ out, int N) {
    int node = blockIdx.x * 4 + (threadIdx.x >> 6);
    if (node >= N) return;
    int lane = threadIdx.x & 63;
    int slot = lane >> 3;        // 0..7: which edge in the group of 8
    int fh   = lane & 7;         // feature pair: features fh*2, fh*2+1
    int beg = row_start[node], end = row_start[node + 1];

    float ax = 0.f, ay = 0.f;

    #define AGG2_BODY(I) {                                                   \
        int sidx = (int)csr_src[(I)];                                        \
        __half2 p = *(const __half2*)(h2 + (size_t)sidx * OUT_F + fh * 2);   \
        float2 f = __half22float2(p);                                        \
        ax += f.x; ay += f.y; }

    int i = beg + slot;
    for (; i + 8 < end; i += 16) { AGG2_BODY(i); AGG2_BODY(i + 8); }
    if (i < end) AGG2_BODY(i);
    #undef AGG2_BODY

    ax += __shfl_xor(ax, 8);  ay += __shfl_xor(ay, 8);
    ax += __shfl_xor(ax, 16); ay += __shfl_xor(ay, 16);
    ax += __shfl_xor(ax, 32); ay += __shfl_xor(ay, 32);

    if (slot == 0) {
        float nd = norm_d[node];
        float2 v;
        v.x = ax * nd + b2[fh * 2];
        v.y = ay * nd + b2[fh * 2 + 1];
        *(float2*)(out + (size_t)node * OUT_F + fh * 2) = v;
    }
}

extern "C" void kernel_launch(void* const* d_in, const int* in_sizes, int n_in,
                              void* d_out, int out_size, void* d_ws, size_t ws_size,
                              hipStream_t stream) {
    const float* feat = (const float*)d_in[0];
    const float* W1   = (const float*)d_in[1];
    const float* b1   = (const float*)d_in[2];
    const float* W2   = (const float*)d_in[3];
    const float* b2   = (const float*)d_in[4];
    const int*   src  = (const int*)d_in[5];
    const int*   dst  = (const int*)d_in[6];

    const int N   = in_sizes[0] / IN_F;       // 50000 (<= MAX_N)
    const int E   = in_sizes[5];              // 1.6M
    const int seg = (E + NSEG - 1) / NSEG;
    const int Wr  = (N + 1) >> 1;
    const int nchunks = (N + SCAN_CHUNK - 1) / SCAN_CHUNK;   // 49

    // ---- workspace layout ----
    float* fws    = (float*)d_ws;
    float* norm_s = fws;                       // N
    float* norm_d = fws + N;                   // N
    __half* h1    = (__half*)(fws + 2 * (size_t)N);          // N*64 halves (reused as h2: N*16 halves)
    float* x1s    = (float*)(h1 + (size_t)N * HID_F);        // N*64 floats
    int*   iws    = (int*)(x1s + (size_t)N * HID_F);
    int*   deg_out   = iws;                    // N
    int*   row_start = iws + N;                // N+1 (counts, then scanned in place)
    int*   bsum      = iws + 2 * N + 1;        // nchunks (+pad to 1024)
    unsigned int* partial = (unsigned int*)(iws + 2 * N + 1 + 1024);        // NSEG*Wr
    unsigned short* csr_src = (unsigned short*)(partial + (size_t)NSEG * Wr); // E u16

    // graph build: LDS histograms (no global atomics, no memsets needed)
    hist_lds_kernel<<<NSEG, 1024, 0, stream>>>(src, partial, E, seg, Wr);
    reduce_prefix_kernel<<<(Wr + 255) / 256, 256, 0, stream>>>(partial, deg_out, Wr, N);
    hist_lds_kernel<<<NSEG, 1024, 0, stream>>>(dst, partial, E, seg, Wr);
    reduce_prefix_kernel<<<(Wr + 255) / 256, 256, 0, stream>>>(partial, row_start, Wr, N);
    norm_kernel<<<(N + 255) / 256, 256, 0, stream>>>(deg_out, row_start, norm_s, norm_d, N);

    // multi-block scan: counts -> exclusive row_start (in place), row_start[N]=E
    scan_local_kernel<<<nchunks, SCAN_BLOCK, 0, stream>>>(row_start, bsum, N);
    scan_bsum_kernel<<<1, 1024, 0, stream>>>(bsum, row_start + N, nchunks);
    scan_add_kernel<<<(N + 255) / 256, 256, 0, stream>>>(row_start, bsum, N);

    scatter_lds_kernel<<<NSEG, 1024, 0, stream>>>(src, dst, row_start, partial, csr_src, E, seg, Wr, N);

    // layer 1
    gemm1_kernel<<<(N + 63) / 64, 256, 0, stream>>>(feat, W1, norm_s, h1, N);
    agg1_kernel<<<(N + 3) / 4, 256, 0, stream>>>(row_start, csr_src, h1, norm_d, norm_s, b1, x1s, N);

    // layer 2 (h2 reuses h1 buffer)
    __half* h2 = h1;
    gemm2_kernel<<<(N + 31) / 32, 256, 0, stream>>>(x1s, W2, h2, N);
    agg2_kernel<<<(N + 3) / 4, 256, 0, stream>>>(row_start, csr_src, h2, norm_d, b2, (float*)d_out, N);
}

// Round 11
// 254.621 us; speedup vs baseline: 2.8889x; 1.0048x over previous
//
#include <hip/hip_runtime.h>
#include <hip/hip_fp16.h>

#define IN_F  128
#define HID_F 64
#define OUT_F 16
#define MAX_N 50176          // max nodes supported by LDS tables (25088 u32 words = 100.4 KB)
#define HWORDS (MAX_N / 2)
#define NSEG  128            // edge segments (one block each in hist; (seg, pass) blocks in scatter)

#define SCAN_ELEMS 4
#define SCAN_BLOCK 256
#define SCAN_CHUNK (SCAN_BLOCK * SCAN_ELEMS)   // 1024 elements per block

#define LSTR 136             // LDS row stride in halves (128 + 8 pad: 2-way-free banks, 16B aligned)

typedef __attribute__((ext_vector_type(8))) _Float16 half8;
typedef __attribute__((ext_vector_type(4))) _Float16 half4v;
typedef __attribute__((ext_vector_type(4))) float    floatx4;

// ---------------------------------------------------------------------------
// 1. per-segment LDS histogram (packed u16 halfwords), no global atomics.
// ---------------------------------------------------------------------------
__global__ __launch_bounds__(1024) void hist_lds_kernel(const int* __restrict__ ids,
                                                        unsigned int* __restrict__ partial,
                                                        int E, int seg, int Wr) {
    __shared__ unsigned int cnt[HWORDS];
    int b = blockIdx.x;
    for (int w = threadIdx.x; w < Wr; w += 1024) cnt[w] = 0;
    __syncthreads();
    int lo = b * seg, hi = min(lo + seg, E);
    for (int e = lo + threadIdx.x; e < hi; e += 1024) {
        int d = ids[e];
        atomicAdd(&cnt[d >> 1], 1u << ((d & 1) * 16));   // LDS atomic
    }
    __syncthreads();
    for (int w = threadIdx.x; w < Wr; w += 1024)
        partial[(size_t)b * Wr + w] = cnt[w];
}

// ---------------------------------------------------------------------------
// 2. reduce partials -> per-node totals; rewrite partials in place as
//    per-(segment,node) EXCLUSIVE prefix (fits u16).
// ---------------------------------------------------------------------------
__global__ __launch_bounds__(256) void reduce_prefix_kernel(unsigned int* __restrict__ partial,
                                                            int* __restrict__ totals,
                                                            int Wr, int N) {
    int w = blockIdx.x * 256 + threadIdx.x;
    if (w >= Wr) return;
    unsigned int r0 = 0, r1 = 0;
    for (int b = 0; b < NSEG; b++) {
        size_t idx = (size_t)b * Wr + w;
        unsigned int v = partial[idx];
        partial[idx] = r0 | (r1 << 16);
        r0 += v & 0xFFFFu;
        r1 += v >> 16;
    }
    int d0 = 2 * w, d1 = 2 * w + 1;
    if (d0 < N) totals[d0] = (int)r0;
    if (d1 < N) totals[d1] = (int)r1;
}

// ---------------------------------------------------------------------------
// 3. norms from int degrees: norm = rsqrt(max(deg,1))
// ---------------------------------------------------------------------------
__global__ __launch_bounds__(256) void norm_kernel(const int* __restrict__ deg_out,
                                                   const int* __restrict__ cnt_in,
                                                   float* __restrict__ norm_s,
                                                   float* __restrict__ norm_d, int N) {
    int i = blockIdx.x * 256 + threadIdx.x;
    if (i < N) {
        norm_s[i] = rsqrtf(fmaxf((float)deg_out[i], 1.0f));
        norm_d[i] = rsqrtf(fmaxf((float)cnt_in[i], 1.0f));
    }
}

// ---------------------------------------------------------------------------
// 4a. multi-block scan phase 1: local exclusive scan per 1024-elem chunk
// ---------------------------------------------------------------------------
__global__ __launch_bounds__(SCAN_BLOCK) void scan_local_kernel(int* __restrict__ counts,
                                                                int* __restrict__ bsum, int N) {
    __shared__ int part[SCAN_BLOCK];
    int t = threadIdx.x;
    int base = blockIdx.x * SCAN_CHUNK + t * SCAN_ELEMS;
    int v[SCAN_ELEMS];
    int s = 0;
    #pragma unroll
    for (int k = 0; k < SCAN_ELEMS; k++) {
        int i = base + k;
        v[k] = (i < N) ? counts[i] : 0;
        s += v[k];
    }
    part[t] = s;
    __syncthreads();
    for (int off = 1; off < SCAN_BLOCK; off <<= 1) {
        int x = (t >= off) ? part[t - off] : 0;
        __syncthreads();
        part[t] += x;
        __syncthreads();
    }
    int run = (t > 0) ? part[t - 1] : 0;
    #pragma unroll
    for (int k = 0; k < SCAN_ELEMS; k++) {
        int i = base + k;
        if (i < N) counts[i] = run;
        run += v[k];
    }
    if (t == SCAN_BLOCK - 1) bsum[blockIdx.x] = part[SCAN_BLOCK - 1];
}

// ---------------------------------------------------------------------------
// 4b. scan phase 2: single tiny block scans chunk totals, writes rowN (=E)
// ---------------------------------------------------------------------------
__global__ __launch_bounds__(1024) void scan_bsum_kernel(int* __restrict__ bsum,
                                                         int* __restrict__ rowN, int nblocks) {
    __shared__ int part[1024];
    int t = threadIdx.x;
    int v = (t < nblocks) ? bsum[t] : 0;
    part[t] = v;
    __syncthreads();
    for (int off = 1; off < 1024; off <<= 1) {
        int x = (t >= off) ? part[t - off] : 0;
        __syncthreads();
        part[t] += x;
        __syncthreads();
    }
    if (t < nblocks) bsum[t] = part[t] - v;   // exclusive
    if (t == 1023) *rowN = part[1023];
}

// ---------------------------------------------------------------------------
// 4c. scan phase 3: add chunk offsets
// ---------------------------------------------------------------------------
__global__ __launch_bounds__(256) void scan_add_kernel(int* __restrict__ counts,
                                                       const int* __restrict__ bsum, int N) {
    int i = blockIdx.x * 256 + threadIdx.x;
    if (i < N) counts[i] += bsum[i / SCAN_CHUNK];
}

// ---------------------------------------------------------------------------
// 5. scatter via LDS cursors. Grid = (NSEG, npass): block (b,p) scans
//    segment b and scatters only dst nodes in range p. No global atomics.
// ---------------------------------------------------------------------------
__global__ __launch_bounds__(1024) void scatter_lds_kernel(const int* __restrict__ src,
                                                           const int* __restrict__ dst,
                                                           const int* __restrict__ row_start,
                                                           const unsigned int* __restrict__ prefix,
                                                           unsigned short* __restrict__ csr_src,
                                                           int E, int seg, int Wr, int N) {
    __shared__ unsigned int pos[HWORDS];
    int b = blockIdx.x;
    int p = blockIdx.y;
    int lo = b * seg, hi = min(lo + seg, E);
    int nlo = p * HWORDS, nhi = min(nlo + HWORDS, N);
    for (int d = nlo + threadIdx.x; d < nhi; d += 1024) {
        unsigned int word = prefix[(size_t)b * Wr + (d >> 1)];
        unsigned int base16 = (word >> ((d & 1) * 16)) & 0xFFFFu;
        pos[d - nlo] = (unsigned int)row_start[d] + base16;
    }
    __syncthreads();
    for (int e = lo + threadIdx.x; e < hi; e += 1024) {
        int d = dst[e];
        if (d >= nlo && d < nhi) {
            unsigned int q = atomicAdd(&pos[d - nlo], 1u);   // LDS atomic
            csr_src[q] = (unsigned short)src[e];
        }
    }
}

// ---------------------------------------------------------------------------
// 6. GEMM1 via MFMA f32_16x16x32_f16: 64 rows/block, fp16 staged inputs,
//    fp32 accumulate, fp16 h output.
// ---------------------------------------------------------------------------
__global__ __launch_bounds__(256) void gemm1_kernel(const float* __restrict__ x,
                                                    const float* __restrict__ W,
                                                    const float* __restrict__ norm_s,
                                                    __half* __restrict__ h, int N) {
    __shared__ _Float16 sx[64 * LSTR];   // 64 rows x 128 k (padded)
    __shared__ _Float16 sw[64 * LSTR];   // 64 n x 128 k (W transposed, padded)
    int t = threadIdx.x;
    int row0 = blockIdx.x * 64;

    for (int i = t; i < IN_F * 16; i += 256) {          // i over (k, n-quad)
        int k = i >> 4, n4 = (i & 15) * 4;
        float4 w4 = *(const float4*)(W + (size_t)k * HID_F + n4);
        sw[(n4 + 0) * LSTR + k] = (_Float16)w4.x;
        sw[(n4 + 1) * LSTR + k] = (_Float16)w4.y;
        sw[(n4 + 2) * LSTR + k] = (_Float16)w4.z;
        sw[(n4 + 3) * LSTR + k] = (_Float16)w4.w;
    }
    for (int i = t; i < 64 * 32; i += 256) {            // i over (row, k-quad)
        int r = i >> 5, k4 = (i & 31) * 4;
        int gr = row0 + r;
        half4v hv = {0, 0, 0, 0};
        if (gr < N) {
            float4 v = *(const float4*)(x + (size_t)gr * IN_F + k4);
            float ns = norm_s[gr];
            hv.x = (_Float16)(v.x * ns); hv.y = (_Float16)(v.y * ns);
            hv.z = (_Float16)(v.z * ns); hv.w = (_Float16)(v.w * ns);
        }
        *(half4v*)(sx + r * LSTR + k4) = hv;
    }
    __syncthreads();

    int wave = t >> 6, lane = t & 63;
    int m = lane & 15, quad = lane >> 4;
    int rbase = wave * 16;

    floatx4 acc[4] = {{0,0,0,0}, {0,0,0,0}, {0,0,0,0}, {0,0,0,0}};
    #pragma unroll
    for (int ks = 0; ks < 4; ks++) {
        half8 av = *(half8*)(sx + (rbase + m) * LSTR + ks * 32 + quad * 8);
        #pragma unroll
        for (int ct = 0; ct < 4; ct++) {
            half8 bv = *(half8*)(sw + (ct * 16 + m) * LSTR + ks * 32 + quad * 8);
            acc[ct] = __builtin_amdgcn_mfma_f32_16x16x32_f16(av, bv, acc[ct], 0, 0, 0);
        }
    }
    #pragma unroll
    for (int ct = 0; ct < 4; ct++) {
        #pragma unroll
        for (int reg = 0; reg < 4; reg++) {
            int gr = row0 + rbase + quad * 4 + reg;
            if (gr < N) h[(size_t)gr * HID_F + ct * 16 + m] = __float2half(acc[ct][reg]);
        }
    }
}

// ---------------------------------------------------------------------------
// 7. CSR aggregation layer 1: wide gather — lane loads half4 (8B), 16 lanes
//    per 128-B row, 4 edges per VMEM instruction; shfl_xor combine.
// ---------------------------------------------------------------------------
__global__ __launch_bounds__(256) void agg1_kernel(const int* __restrict__ row_start,
                                                   const unsigned short* __restrict__ csr_src,
                                                   const __half* __restrict__ h,
                                                   const float* __restrict__ norm_d,
                                                   const float* __restrict__ norm_s,
                                                   const float* __restrict__ b1,
                                                   float* __restrict__ x1s, int N) {
    int node = blockIdx.x * 4 + (threadIdx.x >> 6);
    if (node >= N) return;
    int lane = threadIdx.x & 63;
    int slot = lane >> 4;        // 0..3: which edge in the group of 4
    int fq   = lane & 15;        // feature quad: features fq*4 .. fq*4+3
    int beg = row_start[node], end = row_start[node + 1];

    float ax = 0.f, ay = 0.f, az = 0.f, aw = 0.f;

    #define AGG1_BODY(I) {                                                   \
        int sidx = (int)csr_src[(I)];                                        \
        const uint2* p = (const uint2*)(h + (size_t)sidx * HID_F + fq * 4);  \
        uint2 u = *p;                                                        \
        __half2 p0 = *(__half2*)&u.x, p1 = *(__half2*)&u.y;                  \
        float2 f0 = __half22float2(p0), f1 = __half22float2(p1);             \
        ax += f0.x; ay += f0.y; az += f1.x; aw += f1.y; }

    int i = beg + slot;
    for (; i + 4 < end; i += 8) { AGG1_BODY(i); AGG1_BODY(i + 4); }
    if (i < end) AGG1_BODY(i);
    #undef AGG1_BODY

    ax += __shfl_xor(ax, 16); ay += __shfl_xor(ay, 16);
    az += __shfl_xor(az, 16); aw += __shfl_xor(aw, 16);
    ax += __shfl_xor(ax, 32); ay += __shfl_xor(ay, 32);
    az += __shfl_xor(az, 32); aw += __shfl_xor(aw, 32);

    if (slot == 0) {
        float nd = norm_d[node], ns = norm_s[node];
        const float4 b = *(const float4*)(b1 + fq * 4);
        float4 v;
        v.x = fmaxf(ax * nd + b.x, 0.f) * ns;
        v.y = fmaxf(ay * nd + b.y, 0.f) * ns;
        v.z = fmaxf(az * nd + b.z, 0.f) * ns;
        v.w = fmaxf(aw * nd + b.w, 0.f) * ns;
        *(float4*)(x1s + (size_t)node * HID_F + fq * 4) = v;
    }
}

// ---------------------------------------------------------------------------
// 8. GEMM2 (64 -> 16), output stored fp16
// ---------------------------------------------------------------------------
__global__ __launch_bounds__(256) void gemm2_kernel(const float* __restrict__ x,
                                                    const float* __restrict__ W,
                                                    __half* __restrict__ h2, int N) {
    __shared__ float sW[HID_F * OUT_F];
    __shared__ float sx[32][HID_F + 1];
    for (int i = threadIdx.x; i < HID_F * OUT_F; i += 256) sW[i] = W[i];
    int row0 = blockIdx.x * 32;
    for (int i = threadIdx.x; i < 32 * HID_F; i += 256) {
        int r = i >> 6, k = i & 63;
        int gr = row0 + r;
        sx[r][k] = (gr < N) ? x[(size_t)gr * HID_F + k] : 0.0f;
    }
    __syncthreads();
    int col  = threadIdx.x & 15;
    int rgrp = threadIdx.x >> 4;
    for (int rr = 0; rr < 2; rr++) {
        int r = rgrp * 2 + rr;
        float acc = 0.0f;
        #pragma unroll 8
        for (int k = 0; k < HID_F; k++) acc += sx[r][k] * sW[k * OUT_F + col];
        int gr = row0 + r;
        if (gr < N) h2[(size_t)gr * OUT_F + col] = __float2half(acc);
    }
}

// ---------------------------------------------------------------------------
// 9. CSR aggregation layer 2: lane loads half2 (4B), 8 lanes per 32-B row,
//    8 edges per VMEM instruction; 3-step shfl_xor combine; float2 store.
// ---------------------------------------------------------------------------
__global__ __launch_bounds__(256) void agg2_kernel(const int* __restrict__ row_start,
                                                   const unsigned short* __restrict__ csr_src,
                                                   const __half* __restrict__ h2,
                                                   const float* __restrict__ norm_d,
                                                   const float* __restrict__ b2,
                                                   float* __restrict__ out, int N) {
    int node = blockIdx.x * 4 + (threadIdx.x >> 6);
    if (node >= N) return;
    int lane = threadIdx.x & 63;
    int slot = lane >> 3;        // 0..7: which edge in the group of 8
    int fh   = lane & 7;         // feature pair: features fh*2, fh*2+1
    int beg = row_start[node], end = row_start[node + 1];

    float ax = 0.f, ay = 0.f;

    #define AGG2_BODY(I) {                                                   \
        int sidx = (int)csr_src[(I)];                                        \
        __half2 p = *(const __half2*)(h2 + (size_t)sidx * OUT_F + fh * 2);   \
        float2 f = __half22float2(p);                                        \
        ax += f.x; ay += f.y; }

    int i = beg + slot;
    for (; i + 8 < end; i += 16) { AGG2_BODY(i); AGG2_BODY(i + 8); }
    if (i < end) AGG2_BODY(i);
    #undef AGG2_BODY

    ax += __shfl_xor(ax, 8);  ay += __shfl_xor(ay, 8);
    ax += __shfl_xor(ax, 16); ay += __shfl_xor(ay, 16);
    ax += __shfl_xor(ax, 32); ay += __shfl_xor(ay, 32);

    if (slot == 0) {
        float nd = norm_d[node];
        float2 v;
        v.x = ax * nd + b2[fh * 2];
        v.y = ay * nd + b2[fh * 2 + 1];
        *(float2*)(out + (size_t)node * OUT_F + fh * 2) = v;
    }
}

extern "C" void kernel_launch(void* const* d_in, const int* in_sizes, int n_in,
                              void* d_out, int out_size, void* d_ws, size_t ws_size,
                              hipStream_t stream) {
    const float* feat = (const float*)d_in[0];
    const float* W1   = (const float*)d_in[1];
    const float* b1   = (const float*)d_in[2];
    const float* W2   = (const float*)d_in[3];
    const float* b2   = (const float*)d_in[4];
    const int*   src  = (const int*)d_in[5];
    const int*   dst  = (const int*)d_in[6];

    const int N   = in_sizes[0] / IN_F;       // 50000 (<= MAX_N)
    const int E   = in_sizes[5];              // 1.6M
    const int seg = (E + NSEG - 1) / NSEG;
    const int Wr  = (N + 1) >> 1;
    const int nchunks = (N + SCAN_CHUNK - 1) / SCAN_CHUNK;   // 49
    const int npass   = (N + HWORDS - 1) / HWORDS;           // 2

    // ---- workspace layout (36.0 MB == round-6-proven footprint) ----
    float* fws    = (float*)d_ws;
    float* norm_s = fws;                       // N
    float* norm_d = fws + N;                   // N
    __half* h1    = (__half*)(fws + 2 * (size_t)N);          // N*64 halves (reused as h2: N*16 halves)
    float* x1s    = (float*)(h1 + (size_t)N * HID_F);        // N*64 floats
    int*   iws    = (int*)(x1s + (size_t)N * HID_F);
    int*   deg_out   = iws;                    // N
    int*   row_start = iws + N;                // N+1 (counts, then scanned in place)
    int*   bsum      = iws + 2 * N + 1;        // nchunks (+pad to 1024)
    unsigned int* partial = (unsigned int*)(iws + 2 * N + 1 + 1024);        // NSEG*Wr
    unsigned short* csr_src = (unsigned short*)(partial + (size_t)NSEG * Wr); // E u16

    // graph build: LDS histograms (no global atomics, no memsets needed)
    hist_lds_kernel<<<NSEG, 1024, 0, stream>>>(src, partial, E, seg, Wr);
    reduce_prefix_kernel<<<(Wr + 255) / 256, 256, 0, stream>>>(partial, deg_out, Wr, N);
    hist_lds_kernel<<<NSEG, 1024, 0, stream>>>(dst, partial, E, seg, Wr);
    reduce_prefix_kernel<<<(Wr + 255) / 256, 256, 0, stream>>>(partial, row_start, Wr, N);
    norm_kernel<<<(N + 255) / 256, 256, 0, stream>>>(deg_out, row_start, norm_s, norm_d, N);

    // multi-block scan: counts -> exclusive row_start (in place), row_start[N]=E
    scan_local_kernel<<<nchunks, SCAN_BLOCK, 0, stream>>>(row_start, bsum, N);
    scan_bsum_kernel<<<1, 1024, 0, stream>>>(bsum, row_start + N, nchunks);
    scan_add_kernel<<<(N + 255) / 256, 256, 0, stream>>>(row_start, bsum, N);

    scatter_lds_kernel<<<dim3(NSEG, npass), 1024, 0, stream>>>(src, dst, row_start, partial, csr_src, E, seg, Wr, N);

    // layer 1
    gemm1_kernel<<<(N + 63) / 64, 256, 0, stream>>>(feat, W1, norm_s, h1, N);
    agg1_kernel<<<(N + 3) / 4, 256, 0, stream>>>(row_start, csr_src, h1, norm_d, norm_s, b1, x1s, N);

    // layer 2 (h2 reuses h1 buffer)
    __half* h2 = h1;
    gemm2_kernel<<<(N + 31) / 32, 256, 0, stream>>>(x1s, W2, h2, N);
    agg2_kernel<<<(N + 3) / 4, 256, 0, stream>>>(row_start, csr_src, h2, norm_d, b2, (float*)d_out, N);
}

// Round 12
// 226.605 us; speedup vs baseline: 3.2461x; 1.1236x over previous
//
#include <hip/hip_runtime.h>
#include <hip/hip_fp16.h>

#define IN_F  128
#define HID_F 64
#define OUT_F 16
#define MAX_N 50176          // max nodes supported by LDS tables (25088 u32 words = 100.4 KB)
#define HWORDS (MAX_N / 2)
#define NSEG  128            // edge segments

#define SCAN_ELEMS 4
#define SCAN_BLOCK 256
#define SCAN_CHUNK (SCAN_BLOCK * SCAN_ELEMS)   // 1024 elements per block

#define LSTR 136             // LDS row stride in halves (128 + 8 pad)

typedef __attribute__((ext_vector_type(8))) _Float16 half8;
typedef __attribute__((ext_vector_type(4))) _Float16 half4v;
typedef __attribute__((ext_vector_type(4))) float    floatx4;

// ---------------------------------------------------------------------------
// 1. fused per-segment LDS histograms: grid (NSEG, 2); y=0 -> src, y=1 -> dst.
// ---------------------------------------------------------------------------
__global__ __launch_bounds__(1024) void hist2_kernel(const int* __restrict__ src,
                                                     const int* __restrict__ dst,
                                                     unsigned int* __restrict__ partial,
                                                     int E, int seg, int Wr) {
    __shared__ unsigned int cnt[HWORDS];
    int b = blockIdx.x;
    const int* ids = blockIdx.y ? dst : src;
    unsigned int* pbase = partial + (size_t)blockIdx.y * NSEG * Wr;
    for (int w = threadIdx.x; w < Wr; w += 1024) cnt[w] = 0;
    __syncthreads();
    int lo = b * seg, hi = min(lo + seg, E);
    for (int e = lo + threadIdx.x; e < hi; e += 1024) {
        int d = ids[e];
        atomicAdd(&cnt[d >> 1], 1u << ((d & 1) * 16));   // LDS atomic
    }
    __syncthreads();
    for (int w = threadIdx.x; w < Wr; w += 1024)
        pbase[(size_t)b * Wr + w] = cnt[w];
}

// ---------------------------------------------------------------------------
// 2. fused reduce + norm: grid (ceil(Wr/256), 2).
//    y=0: sum src partials -> norm_s (no write-back).
//    y=1: sum dst partials -> counts + norm_d; rewrite partials as excl prefix.
// ---------------------------------------------------------------------------
__global__ __launch_bounds__(256) void reduce_norm_kernel(unsigned int* __restrict__ partial,
                                                          int* __restrict__ counts,
                                                          float* __restrict__ norm_s,
                                                          float* __restrict__ norm_d,
                                                          int Wr, int N) {
    int w = blockIdx.x * 256 + threadIdx.x;
    if (w >= Wr) return;
    unsigned int r0 = 0, r1 = 0;
    if (blockIdx.y == 0) {
        const unsigned int* base = partial;
        for (int b = 0; b < NSEG; b++) {
            unsigned int v = base[(size_t)b * Wr + w];
            r0 += v & 0xFFFFu; r1 += v >> 16;
        }
        int d0 = 2 * w, d1 = 2 * w + 1;
        if (d0 < N) norm_s[d0] = rsqrtf(fmaxf((float)r0, 1.0f));
        if (d1 < N) norm_s[d1] = rsqrtf(fmaxf((float)r1, 1.0f));
    } else {
        unsigned int* base = partial + (size_t)NSEG * Wr;
        for (int b = 0; b < NSEG; b++) {
            size_t idx = (size_t)b * Wr + w;
            unsigned int v = base[idx];
            base[idx] = r0 | (r1 << 16);
            r0 += v & 0xFFFFu; r1 += v >> 16;
        }
        int d0 = 2 * w, d1 = 2 * w + 1;
        if (d0 < N) { counts[d0] = (int)r0; norm_d[d0] = rsqrtf(fmaxf((float)r0, 1.0f)); }
        if (d1 < N) { counts[d1] = (int)r1; norm_d[d1] = rsqrtf(fmaxf((float)r1, 1.0f)); }
    }
}

// ---------------------------------------------------------------------------
// 3a. multi-block scan phase 1: local exclusive scan per 1024-elem chunk
// ---------------------------------------------------------------------------
__global__ __launch_bounds__(SCAN_BLOCK) void scan_local_kernel(int* __restrict__ counts,
                                                                int* __restrict__ bsum, int N) {
    __shared__ int part[SCAN_BLOCK];
    int t = threadIdx.x;
    int base = blockIdx.x * SCAN_CHUNK + t * SCAN_ELEMS;
    int v[SCAN_ELEMS];
    int s = 0;
    #pragma unroll
    for (int k = 0; k < SCAN_ELEMS; k++) {
        int i = base + k;
        v[k] = (i < N) ? counts[i] : 0;
        s += v[k];
    }
    part[t] = s;
    __syncthreads();
    for (int off = 1; off < SCAN_BLOCK; off <<= 1) {
        int x = (t >= off) ? part[t - off] : 0;
        __syncthreads();
        part[t] += x;
        __syncthreads();
    }
    int run = (t > 0) ? part[t - 1] : 0;
    #pragma unroll
    for (int k = 0; k < SCAN_ELEMS; k++) {
        int i = base + k;
        if (i < N) counts[i] = run;
        run += v[k];
    }
    if (t == SCAN_BLOCK - 1) bsum[blockIdx.x] = part[SCAN_BLOCK - 1];
}

// ---------------------------------------------------------------------------
// 3b. scan phase 2: single tiny block scans chunk totals, writes rowN (=E)
// ---------------------------------------------------------------------------
__global__ __launch_bounds__(1024) void scan_bsum_kernel(int* __restrict__ bsum,
                                                         int* __restrict__ rowN, int nblocks) {
    __shared__ int part[1024];
    int t = threadIdx.x;
    int v = (t < nblocks) ? bsum[t] : 0;
    part[t] = v;
    __syncthreads();
    for (int off = 1; off < 1024; off <<= 1) {
        int x = (t >= off) ? part[t - off] : 0;
        __syncthreads();
        part[t] += x;
        __syncthreads();
    }
    if (t < nblocks) bsum[t] = part[t] - v;   // exclusive
    if (t == 1023) *rowN = part[1023];
}

// ---------------------------------------------------------------------------
// 3c. scan phase 3: add chunk offsets
// ---------------------------------------------------------------------------
__global__ __launch_bounds__(256) void scan_add_kernel(int* __restrict__ counts,
                                                       const int* __restrict__ bsum, int N) {
    int i = blockIdx.x * 256 + threadIdx.x;
    if (i < N) counts[i] += bsum[i / SCAN_CHUNK];
}

// ---------------------------------------------------------------------------
// 4. scatter via LDS cursors. Grid = (NSEG, npass). No global atomics.
// ---------------------------------------------------------------------------
__global__ __launch_bounds__(1024) void scatter_lds_kernel(const int* __restrict__ src,
                                                           const int* __restrict__ dst,
                                                           const int* __restrict__ row_start,
                                                           const unsigned int* __restrict__ prefix,
                                                           unsigned short* __restrict__ csr_src,
                                                           int E, int seg, int Wr, int N) {
    __shared__ unsigned int pos[HWORDS];
    int b = blockIdx.x;
    int p = blockIdx.y;
    int lo = b * seg, hi = min(lo + seg, E);
    int nlo = p * HWORDS, nhi = min(nlo + HWORDS, N);
    for (int d = nlo + threadIdx.x; d < nhi; d += 1024) {
        unsigned int word = prefix[(size_t)b * Wr + (d >> 1)];
        unsigned int base16 = (word >> ((d & 1) * 16)) & 0xFFFFu;
        pos[d - nlo] = (unsigned int)row_start[d] + base16;
    }
    __syncthreads();
    for (int e = lo + threadIdx.x; e < hi; e += 1024) {
        int d = dst[e];
        if (d >= nlo && d < nhi) {
            unsigned int q = atomicAdd(&pos[d - nlo], 1u);   // LDS atomic
            csr_src[q] = (unsigned short)src[e];
        }
    }
}

// ---------------------------------------------------------------------------
// 5. GEMM1 via MFMA f32_16x16x32_f16: 64 rows/block, fp16 staged, fp32 acc.
// ---------------------------------------------------------------------------
__global__ __launch_bounds__(256) void gemm1_kernel(const float* __restrict__ x,
                                                    const float* __restrict__ W,
                                                    const float* __restrict__ norm_s,
                                                    __half* __restrict__ h, int N) {
    __shared__ _Float16 sx[64 * LSTR];   // 64 rows x 128 k (padded)
    __shared__ _Float16 sw[64 * LSTR];   // 64 n x 128 k (W transposed, padded)
    int t = threadIdx.x;
    int row0 = blockIdx.x * 64;

    for (int i = t; i < IN_F * 16; i += 256) {          // i over (k, n-quad)
        int k = i >> 4, n4 = (i & 15) * 4;
        float4 w4 = *(const float4*)(W + (size_t)k * HID_F + n4);
        sw[(n4 + 0) * LSTR + k] = (_Float16)w4.x;
        sw[(n4 + 1) * LSTR + k] = (_Float16)w4.y;
        sw[(n4 + 2) * LSTR + k] = (_Float16)w4.z;
        sw[(n4 + 3) * LSTR + k] = (_Float16)w4.w;
    }
    for (int i = t; i < 64 * 32; i += 256) {            // i over (row, k-quad)
        int r = i >> 5, k4 = (i & 31) * 4;
        int gr = row0 + r;
        half4v hv = {0, 0, 0, 0};
        if (gr < N) {
            float4 v = *(const float4*)(x + (size_t)gr * IN_F + k4);
            float ns = norm_s[gr];
            hv.x = (_Float16)(v.x * ns); hv.y = (_Float16)(v.y * ns);
            hv.z = (_Float16)(v.z * ns); hv.w = (_Float16)(v.w * ns);
        }
        *(half4v*)(sx + r * LSTR + k4) = hv;
    }
    __syncthreads();

    int wave = t >> 6, lane = t & 63;
    int m = lane & 15, quad = lane >> 4;
    int rbase = wave * 16;

    floatx4 acc[4] = {{0,0,0,0}, {0,0,0,0}, {0,0,0,0}, {0,0,0,0}};
    #pragma unroll
    for (int ks = 0; ks < 4; ks++) {
        half8 av = *(half8*)(sx + (rbase + m) * LSTR + ks * 32 + quad * 8);
        #pragma unroll
        for (int ct = 0; ct < 4; ct++) {
            half8 bv = *(half8*)(sw + (ct * 16 + m) * LSTR + ks * 32 + quad * 8);
            acc[ct] = __builtin_amdgcn_mfma_f32_16x16x32_f16(av, bv, acc[ct], 0, 0, 0);
        }
    }
    #pragma unroll
    for (int ct = 0; ct < 4; ct++) {
        #pragma unroll
        for (int reg = 0; reg < 4; reg++) {
            int gr = row0 + rbase + quad * 4 + reg;
            if (gr < N) h[(size_t)gr * HID_F + ct * 16 + m] = __float2half(acc[ct][reg]);
        }
    }
}

// ---------------------------------------------------------------------------
// 6. agg1 + fused epilogue + fused GEMM2: wide gather (half4/lane, 4 edges per
//    VMEM), shfl combine, x1 to LDS, 16-lane matvec with W2, h2 fp16 out.
// ---------------------------------------------------------------------------
__global__ __launch_bounds__(256) void agg1_kernel(const int* __restrict__ row_start,
                                                   const unsigned short* __restrict__ csr_src,
                                                   const __half* __restrict__ h,
                                                   const float* __restrict__ norm_d,
                                                   const float* __restrict__ norm_s,
                                                   const float* __restrict__ b1,
                                                   const float* __restrict__ W2,
                                                   __half* __restrict__ h2, int N) {
    __shared__ float sW2[HID_F * OUT_F];   // 4 KB
    __shared__ float xrow[4][HID_F];       // 1 KB
    int t = threadIdx.x;
    for (int i = t; i < HID_F * OUT_F; i += 256) sW2[i] = W2[i];

    int wave = t >> 6, lane = t & 63;
    int node = blockIdx.x * 4 + wave;
    bool valid = node < N;
    int slot = lane >> 4;        // 0..3
    int fq   = lane & 15;        // feature quad

    float ax = 0.f, ay = 0.f, az = 0.f, aw = 0.f;
    if (valid) {
        int beg = row_start[node], end = row_start[node + 1];

        #define AGG1_BODY(I) {                                                   \
            int sidx = (int)csr_src[(I)];                                        \
            const uint2* p = (const uint2*)(h + (size_t)sidx * HID_F + fq * 4);  \
            uint2 u = *p;                                                        \
            __half2 p0 = *(__half2*)&u.x, p1 = *(__half2*)&u.y;                  \
            float2 f0 = __half22float2(p0), f1 = __half22float2(p1);             \
            ax += f0.x; ay += f0.y; az += f1.x; aw += f1.y; }

        int i = beg + slot;
        for (; i + 4 < end; i += 8) { AGG1_BODY(i); AGG1_BODY(i + 4); }
        if (i < end) AGG1_BODY(i);
        #undef AGG1_BODY

        ax += __shfl_xor(ax, 16); ay += __shfl_xor(ay, 16);
        az += __shfl_xor(az, 16); aw += __shfl_xor(aw, 16);
        ax += __shfl_xor(ax, 32); ay += __shfl_xor(ay, 32);
        az += __shfl_xor(az, 32); aw += __shfl_xor(aw, 32);

        if (slot == 0) {
            float nd = norm_d[node], ns = norm_s[node];
            const float4 b = *(const float4*)(b1 + fq * 4);
            xrow[wave][fq * 4 + 0] = fmaxf(ax * nd + b.x, 0.f) * ns;
            xrow[wave][fq * 4 + 1] = fmaxf(ay * nd + b.y, 0.f) * ns;
            xrow[wave][fq * 4 + 2] = fmaxf(az * nd + b.z, 0.f) * ns;
            xrow[wave][fq * 4 + 3] = fmaxf(aw * nd + b.w, 0.f) * ns;
        }
    }
    __syncthreads();
    if (valid && lane < OUT_F) {
        float acc = 0.0f;
        #pragma unroll 8
        for (int k = 0; k < HID_F; k++)
            acc += xrow[wave][k] * sW2[k * OUT_F + lane];
        h2[(size_t)node * OUT_F + lane] = __float2half(acc);
    }
}

// ---------------------------------------------------------------------------
// 7. agg2: lane loads half2 (4B), 8 lanes per 32-B row, 8 edges per VMEM;
//    3-step shfl_xor combine; fused epilogue; float2 store.
// ---------------------------------------------------------------------------
__global__ __launch_bounds__(256) void agg2_kernel(const int* __restrict__ row_start,
                                                   const unsigned short* __restrict__ csr_src,
                                                   const __half* __restrict__ h2,
                                                   const float* __restrict__ norm_d,
                                                   const float* __restrict__ b2,
                                                   float* __restrict__ out, int N) {
    int node = blockIdx.x * 4 + (threadIdx.x >> 6);
    if (node >= N) return;
    int lane = threadIdx.x & 63;
    int slot = lane >> 3;        // 0..7
    int fh   = lane & 7;         // feature pair
    int beg = row_start[node], end = row_start[node + 1];

    float ax = 0.f, ay = 0.f;

    #define AGG2_BODY(I) {                                                   \
        int sidx = (int)csr_src[(I)];                                        \
        __half2 p = *(const __half2*)(h2 + (size_t)sidx * OUT_F + fh * 2);   \
        float2 f = __half22float2(p);                                        \
        ax += f.x; ay += f.y; }

    int i = beg + slot;
    for (; i + 8 < end; i += 16) { AGG2_BODY(i); AGG2_BODY(i + 8); }
    if (i < end) AGG2_BODY(i);
    #undef AGG2_BODY

    ax += __shfl_xor(ax, 8);  ay += __shfl_xor(ay, 8);
    ax += __shfl_xor(ax, 16); ay += __shfl_xor(ay, 16);
    ax += __shfl_xor(ax, 32); ay += __shfl_xor(ay, 32);

    if (slot == 0) {
        float nd = norm_d[node];
        float2 v;
        v.x = ax * nd + b2[fh * 2];
        v.y = ay * nd + b2[fh * 2 + 1];
        *(float2*)(out + (size_t)node * OUT_F + fh * 2) = v;
    }
}

extern "C" void kernel_launch(void* const* d_in, const int* in_sizes, int n_in,
                              void* d_out, int out_size, void* d_ws, size_t ws_size,
                              hipStream_t stream) {
    const float* feat = (const float*)d_in[0];
    const float* W1   = (const float*)d_in[1];
    const float* b1   = (const float*)d_in[2];
    const float* W2   = (const float*)d_in[3];
    const float* b2   = (const float*)d_in[4];
    const int*   src  = (const int*)d_in[5];
    const int*   dst  = (const int*)d_in[6];

    const int N   = in_sizes[0] / IN_F;       // 50000 (<= MAX_N)
    const int E   = in_sizes[5];              // 1.6M
    const int seg = (E + NSEG - 1) / NSEG;
    const int Wr  = (N + 1) >> 1;
    const int nchunks = (N + SCAN_CHUNK - 1) / SCAN_CHUNK;   // 49
    const int npass   = (N + HWORDS - 1) / HWORDS;           // 2

    // ---- workspace layout (~49 MB; ws_size = 256 MiB per harness fill) ----
    float* fws    = (float*)d_ws;
    float* norm_s = fws;                       // N
    float* norm_d = fws + N;                   // N
    __half* h1    = (__half*)(fws + 2 * (size_t)N);          // N*64 halves
    __half* h2    = h1 + (size_t)N * HID_F;                  // N*16 halves (disjoint: agg1 reads h1 while writing h2)
    int*   iws    = (int*)(h2 + (size_t)N * OUT_F);
    int*   row_start = iws;                    // N+1 (counts, then scanned in place)
    int*   bsum      = iws + N + 1;            // nchunks (+pad to 1024)
    unsigned int* partial = (unsigned int*)(iws + N + 1 + 1024);   // 2 * NSEG*Wr (src then dst)
    unsigned short* csr_src = (unsigned short*)(partial + 2 * (size_t)NSEG * Wr); // E u16

    // graph build: fused histograms + fused reduce/norm (no global atomics)
    hist2_kernel<<<dim3(NSEG, 2), 1024, 0, stream>>>(src, dst, partial, E, seg, Wr);
    reduce_norm_kernel<<<dim3((Wr + 255) / 256, 2), 256, 0, stream>>>(partial, row_start, norm_s, norm_d, Wr, N);

    // multi-block scan: counts -> exclusive row_start (in place), row_start[N]=E
    scan_local_kernel<<<nchunks, SCAN_BLOCK, 0, stream>>>(row_start, bsum, N);
    scan_bsum_kernel<<<1, 1024, 0, stream>>>(bsum, row_start + N, nchunks);
    scan_add_kernel<<<(N + 255) / 256, 256, 0, stream>>>(row_start, bsum, N);

    scatter_lds_kernel<<<dim3(NSEG, npass), 1024, 0, stream>>>(src, dst, row_start,
                                                               partial + (size_t)NSEG * Wr,
                                                               csr_src, E, seg, Wr, N);

    // layer 1 projection, then fused agg1+epilogue+gemm2, then agg2+epilogue
    gemm1_kernel<<<(N + 63) / 64, 256, 0, stream>>>(feat, W1, norm_s, h1, N);
    agg1_kernel<<<(N + 3) / 4, 256, 0, stream>>>(row_start, csr_src, h1, norm_d, norm_s, b1, W2, h2, N);
    agg2_kernel<<<(N + 3) / 4, 256, 0, stream>>>(row_start, csr_src, h2, norm_d, b2, (float*)d_out, N);
}